// Round 3
// baseline (695.094 us; speedup 1.0000x reference)
//
#include <hip/hip_runtime.h>
#include <hip/hip_bf16.h>
#include <math.h>

#define HW_ (192*192)
#define Wd 192
#define HIDc 127

// fp32 weight-copy offsets inside ws "wts" region
#define O_LN1W 0
#define O_QKVW 96
#define O_QKVB 7008
#define O_RPB  7152
#define O_PROJW 7490
#define O_PROJB 9794
#define O_ECA  9842
#define O_LN2W 9849
#define O_WIN  9945
#define O_WDW  22137
#define O_WOUT 24423
#define WTS_LEN 30519

typedef unsigned short ushort_t;

__device__ __forceinline__ float b2f(__hip_bfloat16 v){ return __bfloat162float(v); }
__device__ __forceinline__ float u2f(ushort_t h){ return __uint_as_float(((unsigned)h)<<16); }
__device__ __forceinline__ ushort_t f2u(float f){
    __hip_bfloat16 h = __float2bfloat16(f);
    union { __hip_bfloat16 b; ushort_t u; } c; c.b = h; return c.u;
}

__device__ __forceinline__ int wstart(int i){
    // L=192, K=7, DIL=3 closed form of _window_starts
    if (i < 9) return i % 3;
    if (i >= 183) return 171 + (i % 3);
    return i - 9;
}

// ------------- Kernel A: detect input dtype (bf16 vs fp32) ----------------------
__global__ void detect_kernel(const ushort_t* __restrict__ xu, int* __restrict__ mode)
{
    __shared__ int sbad;
    if (threadIdx.x == 0) sbad = 0;
    __syncthreads();
    int bad = 0;
    for (int t = threadIdx.x; t < 16384; t += 256){
        unsigned int u = xu[2*t];
        float f = __uint_as_float(u << 16);
        if (!(fabsf(f) < 100.f)) bad++;
    }
    atomicAdd(&sbad, bad);
    __syncthreads();
    if (threadIdx.x == 0) mode[0] = (sbad > 1000) ? 1 : 0;
}

// ------------- Kernel B: convert all weight tensors to fp32 in ws ---------------
__global__ void convert_kernel(
    const void* p0, const void* p1, const void* p2, const void* p3,
    const void* p4, const void* p5, const void* p6, const void* p7,
    const void* p8, const void* p9, const void* p10, const void* p11,
    const void* p12, const int* __restrict__ mode, float* __restrict__ wts)
{
    const void* ps[13] = {p0,p1,p2,p3,p4,p5,p6,p7,p8,p9,p10,p11,p12};
    const int sz[13]  = {48,48,6912,144,338,2304,48,7,48,48,12192,2286,6096};
    const int off[13] = {O_LN1W,48,O_QKVW,O_QKVB,O_RPB,O_PROJW,O_PROJB,O_ECA,
                         O_LN2W,9897,O_WIN,O_WDW,O_WOUT};
    int b = blockIdx.x;
    int n = sz[b];
    float* dst = wts + off[b];
    if (mode[0]){
        const float* s = (const float*)ps[b];
        for (int i = threadIdx.x; i < n; i += 256) dst[i] = s[i];
    } else {
        const __hip_bfloat16* s = (const __hip_bfloat16*)ps[b];
        for (int i = threadIdx.x; i < n; i += 256) dst[i] = b2f(s[i]);
    }
}

// ------------- Kernel 1: LN1 + QKV proj (6 thr/px) + ECA channel-sum ------------
// block: 192 thr = 32 px * 6 r-groups (24 outputs each). q/k/v out = bf16 [p][48].
__global__ __launch_bounds__(192) void ln1qkv_kernel(
    const void* __restrict__ x, const int* __restrict__ mode,
    const float* __restrict__ wts,
    ushort_t* __restrict__ q, ushort_t* __restrict__ k, ushort_t* __restrict__ v,
    float* __restrict__ chsum)
{
    __shared__ float sw[144*48];          // 27648 B
    __shared__ float sx[32*49];           // 6272 B (pad 49)
    __shared__ float sb[144];
    __shared__ float sln[96];
    __shared__ ushort_t sstage[3][32*48]; // 9216 B

    const int tid = threadIdx.x;
    const int px_l = tid & 31;
    const int r6   = tid >> 5;            // 0..5, wave-uniform in pairs
    const int p0   = blockIdx.x * 32;
    const int p    = p0 + px_l;

    for (int i = tid; i < 144*48; i += 192) sw[i] = wts[O_QKVW + i];
    for (int i = tid; i < 144;    i += 192) sb[i] = wts[O_QKVB + i];
    for (int i = tid; i < 96;     i += 192) sln[i] = wts[O_LN1W + i];

    // x tile load, planar-coalesced
    if (mode[0]){
        const float* xf = (const float*)x;
        for (int idx = tid; idx < 32*48; idx += 192){
            int c = idx >> 5, pl = idx & 31;
            sx[pl*49 + c] = xf[c*HW_ + p0 + pl];
        }
    } else {
        const __hip_bfloat16* xb = (const __hip_bfloat16*)x;
        for (int idx = tid; idx < 32*48; idx += 192){
            int c = idx >> 5, pl = idx & 31;
            sx[pl*49 + c] = b2f(xb[c*HW_ + p0 + pl]);
        }
    }
    __syncthreads();

    float xr[48];
    float mu = 0.f;
    #pragma unroll
    for (int c = 0; c < 48; c++){ xr[c] = sx[px_l*49 + c]; mu += xr[c]; }
    mu *= (1.f/48.f);
    float var = 0.f;
    #pragma unroll
    for (int c = 0; c < 48; c++){ float d = xr[c]-mu; var += d*d; }
    var *= (1.f/48.f);
    float rs = rsqrtf(var + 1e-5f);
    #pragma unroll
    for (int c = 0; c < 48; c++) xr[c] = (xr[c]-mu)*rs*sln[c] + sln[48+c];

    // ECA channel-sum: wave 0 only (lanes 0..31 px with r6=0, 32..63 same px r6=1)
    if (tid < 64){
        #pragma unroll
        for (int c = 0; c < 48; c++){
            float s = xr[c];
            s += __shfl_xor(s, 1);  s += __shfl_xor(s, 2);  s += __shfl_xor(s, 4);
            s += __shfl_xor(s, 8);  s += __shfl_xor(s, 16); s += __shfl_xor(s, 32);
            if (tid == 0) atomicAdd(&chsum[c], s * 0.5f);   // halves double-count
        }
    }

    const int rbase = r6 * 24;
    const float scale = (r6 < 2) ? 0.20412414523193154f : 1.0f;
    ushort_t* sp = sstage[r6 >> 1];
    const int scol = (r6 & 1) * 24;
    #pragma unroll 4
    for (int ro = 0; ro < 24; ro++){
        int r = rbase + ro;
        float acc = sb[r];
        const float4* swr = (const float4*)&sw[r*48];
        #pragma unroll
        for (int c4 = 0; c4 < 12; c4++){
            float4 w = swr[c4];
            acc += w.x*xr[4*c4] + w.y*xr[4*c4+1] + w.z*xr[4*c4+2] + w.w*xr[4*c4+3];
        }
        sp[px_l*48 + scol + ro] = f2u(acc * scale);
    }
    __syncthreads();

    // coalesced copy-out: 3 tensors * 768 dwords each
    unsigned int* qd = (unsigned int*)q + p0*24;
    unsigned int* kd = (unsigned int*)k + p0*24;
    unsigned int* vd = (unsigned int*)v + p0*24;
    const unsigned int* src = (const unsigned int*)&sstage[0][0];
    for (int idx = tid; idx < 3*768; idx += 192){
        int tsr = idx / 768, d = idx - tsr*768;
        unsigned int val = src[idx];
        (tsr == 0 ? qd : tsr == 1 ? kd : vd)[d] = val;
    }
}

// ------------- Kernel 2: pooled mean -> ECA conv1d(k=7,pad=3) -> sigmoid --------
__global__ void gate_kernel(const float* __restrict__ chsum,
                            const float* __restrict__ wts,
                            float* __restrict__ gate)
{
    __shared__ float m[48];
    int t = threadIdx.x;
    if (t < 48) m[t] = chsum[t] * (1.f / (float)HW_);
    __syncthreads();
    if (t < 48){
        float acc = 0.f;
        for (int kk = 0; kk < 7; kk++){
            int c = t + kk - 3;
            if (c >= 0 && c < 48) acc += wts[O_ECA + kk] * m[c];
        }
        gate[t] = 1.f / (1.f + expf(-acc));
    }
}

// ------------- Kernel 3: neighborhood attention (K=7, DIL=3), bf16 gathers ------
// grid (HW/128, 2 heads), block 256: 2 lanes per (px); each lane handles 12 ch.
__global__ __launch_bounds__(256) void attn_kernel(
    const ushort_t* __restrict__ q, const ushort_t* __restrict__ k,
    const ushort_t* __restrict__ v, const float* __restrict__ wts,
    float* __restrict__ aout)
{
    const int head = blockIdx.y;
    __shared__ float srpb[169];
    for (int i = threadIdx.x; i < 169; i += 256) srpb[i] = wts[O_RPB + head*169 + i];
    __syncthreads();

    const int tid  = threadIdx.x;
    const int px   = blockIdx.x * 128 + (tid >> 1);
    const int half = tid & 1;
    const int i = px / Wd, j = px % Wd;
    const int sti = wstart(i), stj = wstart(j);
    const int pbi = (sti - i) / 3 + 6;
    const int pbj = (stj - j) / 3 + 6;
    const int choff = head*24 + half*12;

    float qr[12];
    {
        const ushort4* qp = (const ushort4*)(q + px*48 + choff);
        #pragma unroll
        for (int b = 0; b < 3; b++){
            ushort4 uu = qp[b];
            qr[4*b]   = u2f(uu.x); qr[4*b+1] = u2f(uu.y);
            qr[4*b+2] = u2f(uu.z); qr[4*b+3] = u2f(uu.w);
        }
    }

    float l[49];
    float mx = -1e30f;
    #pragma unroll
    for (int xx = 0; xx < 7; xx++){
        int ii = sti + 3*xx;
        #pragma unroll
        for (int yy = 0; yy < 7; yy++){
            int jj = stj + 3*yy;
            const ushort4* kp = (const ushort4*)(k + (ii*Wd + jj)*48 + choff);
            float acc = 0.f;
            #pragma unroll
            for (int b = 0; b < 3; b++){
                ushort4 uu = kp[b];
                acc += qr[4*b]*u2f(uu.x) + qr[4*b+1]*u2f(uu.y)
                     + qr[4*b+2]*u2f(uu.z) + qr[4*b+3]*u2f(uu.w);
            }
            acc += __shfl_xor(acc, 1);               // combine channel halves
            acc += srpb[(pbi+xx)*13 + (pbj+yy)];
            l[xx*7+yy] = acc;
            mx = fmaxf(mx, acc);
        }
    }
    float s = 0.f;
    #pragma unroll
    for (int t = 0; t < 49; t++){ l[t] = __expf(l[t]-mx); s += l[t]; }
    float inv = 1.f / s;

    float acc[12];
    #pragma unroll
    for (int c = 0; c < 12; c++) acc[c] = 0.f;
    #pragma unroll
    for (int xx = 0; xx < 7; xx++){
        int ii = sti + 3*xx;
        #pragma unroll
        for (int yy = 0; yy < 7; yy++){
            const ushort4* vp = (const ushort4*)(v + (ii*Wd + stj + 3*yy)*48 + choff);
            float wgt = l[xx*7+yy] * inv;
            #pragma unroll
            for (int b = 0; b < 3; b++){
                ushort4 uu = vp[b];
                acc[4*b]   += wgt*u2f(uu.x); acc[4*b+1] += wgt*u2f(uu.y);
                acc[4*b+2] += wgt*u2f(uu.z); acc[4*b+3] += wgt*u2f(uu.w);
            }
        }
    }
    // planar fp32 out, coalesced (even lanes ch c, odd lanes ch 12+c)
    #pragma unroll
    for (int c = 0; c < 12; c++)
        aout[(choff + c)*HW_ + px] = acc[c];
}

// ------------- Kernel 4: proj + gate + residual (x2 = x + proj(aout)*gate) ------
// block 256 = 64 px * 4 wave-uniform o-groups (12 outputs each)
__global__ __launch_bounds__(256) void proj_kernel(
    const float* __restrict__ aout, const float* __restrict__ wts,
    const float* __restrict__ gate, const void* __restrict__ x,
    const int* __restrict__ mode, float* __restrict__ x2)
{
    __shared__ float sw[48*48];
    __shared__ float sbias[48];
    __shared__ float sg[48];
    const int tid = threadIdx.x;
    for (int i = tid; i < 2304; i += 256) sw[i] = wts[O_PROJW + i];
    if (tid < 48){
        sbias[tid] = wts[O_PROJB + tid];
        sg[tid]    = gate[tid];
    }
    __syncthreads();

    const int px = blockIdx.x * 64 + (tid & 63);
    const int og = tid >> 6;          // 0..3, wave-uniform
    const int ob = og * 12;

    float ar[48];
    #pragma unroll
    for (int c = 0; c < 48; c++) ar[c] = aout[c*HW_ + px];

    const float* xf = (const float*)x;
    const __hip_bfloat16* xb = (const __hip_bfloat16*)x;
    const int md = mode[0];
    #pragma unroll 2
    for (int oo = 0; oo < 12; oo++){
        int o = ob + oo;
        float acc = sbias[o];
        const float4* swr = (const float4*)&sw[o*48];
        #pragma unroll
        for (int c4 = 0; c4 < 12; c4++){
            float4 w = swr[c4];
            acc += w.x*ar[4*c4] + w.y*ar[4*c4+1] + w.z*ar[4*c4+2] + w.w*ar[4*c4+3];
        }
        float res = md ? xf[o*HW_ + px] : b2f(xb[o*HW_ + px]);
        x2[o*HW_ + px] = res + acc * sg[o];
    }
}

// ------------- Kernel 5: LN2 (inline) + pointwise1 (48 -> 254), bf16 out --------
__global__ __launch_bounds__(128) void pw1_kernel(
    const float* __restrict__ x2, const float* __restrict__ wts,
    ushort_t* __restrict__ t)
{
    int ob   = blockIdx.y * 64;
    int ocnt = min(64, 254 - ob);
    __shared__ float sw[64*48];
    __shared__ float sln[96];
    for (int i = threadIdx.x; i < ocnt*48; i += 128) sw[i] = wts[O_WIN + ob*48 + i];
    for (int i = threadIdx.x; i < 96;      i += 128) sln[i] = wts[O_LN2W + i];
    __syncthreads();

    int p = blockIdx.x * 128 + threadIdx.x;
    float xr[48];
    float mu = 0.f;
    #pragma unroll
    for (int c = 0; c < 48; c++){ xr[c] = x2[c*HW_ + p]; mu += xr[c]; }
    mu *= (1.f/48.f);
    float var = 0.f;
    #pragma unroll
    for (int c = 0; c < 48; c++){ float d = xr[c]-mu; var += d*d; }
    var *= (1.f/48.f);
    float rs = rsqrtf(var + 1e-5f);
    #pragma unroll
    for (int c = 0; c < 48; c++) xr[c] = (xr[c]-mu)*rs*sln[c] + sln[48+c];

    for (int o = 0; o < ocnt; o++){
        float acc = 0.f;
        const float4* swr = (const float4*)&sw[o*48];
        #pragma unroll
        for (int c4 = 0; c4 < 12; c4++){
            float4 w = swr[c4];
            acc += w.x*xr[4*c4] + w.y*xr[4*c4+1] + w.z*xr[4*c4+2] + w.w*xr[4*c4+3];
        }
        t[(ob+o)*HW_ + p] = f2u(acc);
    }
}

// ------------- Kernel 6: depthwise 3x3 + exact GeLU gating, bf16 in/out ---------
__global__ __launch_bounds__(256) void dw_kernel(
    const ushort_t* __restrict__ t, const float* __restrict__ wts,
    ushort_t* __restrict__ g)
{
    int ch = blockIdx.y;               // 0..126
    int p  = blockIdx.x * 256 + threadIdx.x;
    int i  = p / Wd, j = p % Wd;
    float w1[9], w2[9];
    #pragma unroll
    for (int s = 0; s < 9; s++){
        w1[s] = wts[O_WDW + ch*9 + s];
        w2[s] = wts[O_WDW + (ch+HIDc)*9 + s];
    }
    const ushort_t* t1 = t + (size_t)ch * HW_;
    const ushort_t* t2 = t + (size_t)(ch+HIDc) * HW_;
    float a1 = 0.f, a2 = 0.f;
    #pragma unroll
    for (int di = 0; di < 3; di++){
        int ii = i + di - 1;
        if (ii < 0 || ii >= 192) continue;
        #pragma unroll
        for (int dj = 0; dj < 3; dj++){
            int jj = j + dj - 1;
            if (jj < 0 || jj >= 192) continue;
            int off = ii*Wd + jj;
            a1 += w1[di*3+dj]*u2f(t1[off]);
            a2 += w2[di*3+dj]*u2f(t2[off]);
        }
    }
    float ge = a1 * 0.5f * (1.f + erff(a1 * 0.70710678118654752f)); // exact gelu
    g[(size_t)ch*HW_ + p] = f2u(ge * a2);
}

// ------------- Kernel 7: pointwise2 (127 -> 24x2) + final residual --------------
__global__ __launch_bounds__(128) void pw2_kernel(
    const ushort_t* __restrict__ g, const float* __restrict__ wts,
    const float* __restrict__ x2, void* __restrict__ outv,
    const int* __restrict__ mode)
{
    int ob = blockIdx.y * 24;          // 2 chunks of 24 output channels
    __shared__ float sw[24*127];
    for (int i = threadIdx.x; i < 24*127; i += 128) sw[i] = wts[O_WOUT + ob*127 + i];
    __syncthreads();

    int p = blockIdx.x * 128 + threadIdx.x;
    float acc[24];
    #pragma unroll
    for (int o = 0; o < 24; o++) acc[o] = 0.f;
    for (int c = 0; c < 127; c++){
        float gv = u2f(g[(size_t)c*HW_ + p]);
        #pragma unroll
        for (int o = 0; o < 24; o++) acc[o] += sw[o*127+c]*gv;
    }
    if (mode[0]){
        float* out = (float*)outv;
        #pragma unroll
        for (int o = 0; o < 24; o++){
            int oc = ob + o;
            out[(size_t)oc*HW_ + p] = x2[(size_t)oc*HW_ + p] + acc[o];
        }
    } else {
        __hip_bfloat16* out = (__hip_bfloat16*)outv;
        #pragma unroll
        for (int o = 0; o < 24; o++){
            int oc = ob + o;
            out[(size_t)oc*HW_ + p] =
                __float2bfloat16(x2[(size_t)oc*HW_ + p] + acc[o]);
        }
    }
}

extern "C" void kernel_launch(void* const* d_in, const int* in_sizes, int n_in,
                              void* d_out, int out_size, void* d_ws, size_t ws_size,
                              hipStream_t stream)
{
    (void)in_sizes; (void)n_in; (void)out_size;

    char* ws = (char*)d_ws;
    // region R (aliased): t bf16 [254][HW] = 18,726,912 B; inside it live
    //   q,k,v bf16 [HW][48] (3,538,944 B each) + aout fp32 [48][HW] (7,077,888 B)
    ushort_t* q    = (ushort_t*)(ws);
    ushort_t* k    = (ushort_t*)(ws + 3538944);
    ushort_t* v    = (ushort_t*)(ws + 7077888);
    float*    aout = (float*)   (ws + 10616832);
    ushort_t* t    = (ushort_t*)(ws);
    float*    x2   = (float*)   (ws + 18726912);
    ushort_t* g    = (ushort_t*)(ws + 25804800);
    float*    chsum= (float*)   (ws + 35168256);
    float*    gate = (float*)   (ws + 35168448);
    int*      mode = (int*)     (ws + 35168640);
    float*    wts  = (float*)   (ws + 35168656);

    size_t need = 35168656 + (size_t)WTS_LEN*4;
    if (ws_size < need) return;

    hipMemsetAsync(chsum, 0, 48*sizeof(float), stream);

    detect_kernel<<<1, 256, 0, stream>>>((const ushort_t*)d_in[0], mode);
    convert_kernel<<<13, 256, 0, stream>>>(
        d_in[1], d_in[2], d_in[3], d_in[4], d_in[5], d_in[6], d_in[7],
        d_in[8], d_in[9], d_in[10], d_in[11], d_in[12], d_in[13], mode, wts);

    ln1qkv_kernel<<<dim3(HW_/32), 192, 0, stream>>>(d_in[0], mode, wts,
                                                    q, k, v, chsum);
    gate_kernel<<<1, 64, 0, stream>>>(chsum, wts, gate);
    attn_kernel<<<dim3(HW_/128, 2), 256, 0, stream>>>(q, k, v, wts, aout);
    proj_kernel<<<dim3(HW_/64), 256, 0, stream>>>(aout, wts, gate, d_in[0],
                                                  mode, x2);
    pw1_kernel<<<dim3(HW_/128, 4), 128, 0, stream>>>(x2, wts, t);
    dw_kernel<<<dim3(HW_/256, 127), 256, 0, stream>>>(t, wts, g);
    pw2_kernel<<<dim3(HW_/128, 2), 128, 0, stream>>>(g, wts, x2, d_out, mode);
}

// Round 4
// 379.559 us; speedup vs baseline: 1.8313x; 1.8313x over previous
//
#include <hip/hip_runtime.h>
#include <hip/hip_bf16.h>
#include <math.h>

#define HW_ (192*192)
#define Wd 192
#define HIDc 127
#define NBLK1 (HW_/32)   // 1152 ln1qkv blocks

// fp32 weight-copy offsets inside ws "wts" region
#define O_LN1W 0
#define O_QKVW 96
#define O_QKVB 7008
#define O_RPB  7152
#define O_PROJW 7490
#define O_PROJB 9794
#define O_ECA  9842
#define O_LN2W 9849
#define O_WIN  9945
#define O_WDW  22137
#define O_WOUT 24423
#define WTS_LEN 30519

typedef unsigned short ushort_t;

__device__ __forceinline__ float b2f(__hip_bfloat16 v){ return __bfloat162float(v); }
__device__ __forceinline__ float u2f(ushort_t h){ return __uint_as_float(((unsigned)h)<<16); }
__device__ __forceinline__ ushort_t f2u(float f){
    __hip_bfloat16 h = __float2bfloat16(f);
    union { __hip_bfloat16 b; ushort_t u; } c; c.b = h; return c.u;
}

__device__ __forceinline__ int wstart(int i){
    // L=192, K=7, DIL=3 closed form of _window_starts
    if (i < 9) return i % 3;
    if (i >= 183) return 171 + (i % 3);
    return i - 9;
}

// ------------- Kernel A: detect input dtype (bf16 vs fp32) ----------------------
__global__ void detect_kernel(const ushort_t* __restrict__ xu, int* __restrict__ mode)
{
    __shared__ int sbad;
    if (threadIdx.x == 0) sbad = 0;
    __syncthreads();
    int bad = 0;
    for (int t = threadIdx.x; t < 16384; t += 256){
        unsigned int u = xu[2*t];
        float f = __uint_as_float(u << 16);
        if (!(fabsf(f) < 100.f)) bad++;
    }
    atomicAdd(&sbad, bad);
    __syncthreads();
    if (threadIdx.x == 0) mode[0] = (sbad > 1000) ? 1 : 0;
}

// ------------- Kernel B: convert all weight tensors to fp32 in ws ---------------
__global__ void convert_kernel(
    const void* p0, const void* p1, const void* p2, const void* p3,
    const void* p4, const void* p5, const void* p6, const void* p7,
    const void* p8, const void* p9, const void* p10, const void* p11,
    const void* p12, const int* __restrict__ mode, float* __restrict__ wts)
{
    const void* ps[13] = {p0,p1,p2,p3,p4,p5,p6,p7,p8,p9,p10,p11,p12};
    const int sz[13]  = {48,48,6912,144,338,2304,48,7,48,48,12192,2286,6096};
    const int off[13] = {O_LN1W,48,O_QKVW,O_QKVB,O_RPB,O_PROJW,O_PROJB,O_ECA,
                         O_LN2W,9897,O_WIN,O_WDW,O_WOUT};
    int b = blockIdx.x;
    int n = sz[b];
    float* dst = wts + off[b];
    if (mode[0]){
        const float* s = (const float*)ps[b];
        for (int i = threadIdx.x; i < n; i += 256) dst[i] = s[i];
    } else {
        const __hip_bfloat16* s = (const __hip_bfloat16*)ps[b];
        for (int i = threadIdx.x; i < n; i += 256) dst[i] = b2f(s[i]);
    }
}

// ------------- Kernel 1: LN1 + QKV proj (6 thr/px) + ECA partial sums -----------
// block: 192 thr = 32 px * 6 r-groups (24 outputs each). q/k/v out = bf16 [p][48].
// ECA: per-block partials to chpart[blk][48] -- NO global atomics.
__global__ __launch_bounds__(192) void ln1qkv_kernel(
    const void* __restrict__ x, const int* __restrict__ mode,
    const float* __restrict__ wts,
    ushort_t* __restrict__ q, ushort_t* __restrict__ k, ushort_t* __restrict__ v,
    float* __restrict__ chpart)
{
    __shared__ float sw[144*48];          // 27648 B
    __shared__ float sx[32*49];           // 6272 B (pad 49)
    __shared__ float sb[144];
    __shared__ float sln[96];
    __shared__ ushort_t sstage[3][32*48]; // 9216 B

    const int tid = threadIdx.x;
    const int px_l = tid & 31;
    const int r6   = tid >> 5;            // 0..5, wave-uniform in pairs
    const int p0   = blockIdx.x * 32;

    for (int i = tid; i < 144*48; i += 192) sw[i] = wts[O_QKVW + i];
    for (int i = tid; i < 144;    i += 192) sb[i] = wts[O_QKVB + i];
    for (int i = tid; i < 96;     i += 192) sln[i] = wts[O_LN1W + i];

    // x tile load, planar-coalesced
    if (mode[0]){
        const float* xf = (const float*)x;
        for (int idx = tid; idx < 32*48; idx += 192){
            int c = idx >> 5, pl = idx & 31;
            sx[pl*49 + c] = xf[c*HW_ + p0 + pl];
        }
    } else {
        const __hip_bfloat16* xb = (const __hip_bfloat16*)x;
        for (int idx = tid; idx < 32*48; idx += 192){
            int c = idx >> 5, pl = idx & 31;
            sx[pl*49 + c] = b2f(xb[c*HW_ + p0 + pl]);
        }
    }
    __syncthreads();

    float xr[48];
    float mu = 0.f;
    #pragma unroll
    for (int c = 0; c < 48; c++){ xr[c] = sx[px_l*49 + c]; mu += xr[c]; }
    mu *= (1.f/48.f);
    float var = 0.f;
    #pragma unroll
    for (int c = 0; c < 48; c++){ float d = xr[c]-mu; var += d*d; }
    var *= (1.f/48.f);
    float rs = rsqrtf(var + 1e-5f);
    #pragma unroll
    for (int c = 0; c < 48; c++) xr[c] = (xr[c]-mu)*rs*sln[c] + sln[48+c];

    // ECA per-block partials: wave 0 (lanes 0..31 = px r6=0, 32..63 same px r6=1)
    if (tid < 64){
        #pragma unroll
        for (int c = 0; c < 48; c++){
            float s = xr[c];
            s += __shfl_xor(s, 1);  s += __shfl_xor(s, 2);  s += __shfl_xor(s, 4);
            s += __shfl_xor(s, 8);  s += __shfl_xor(s, 16); s += __shfl_xor(s, 32);
            if (tid == 0) chpart[blockIdx.x*48 + c] = s * 0.5f;  // halves double-count
        }
    }

    const int rbase = r6 * 24;
    const float scale = (r6 < 2) ? 0.20412414523193154f : 1.0f;
    ushort_t* sp = sstage[r6 >> 1];
    const int scol = (r6 & 1) * 24;
    #pragma unroll 4
    for (int ro = 0; ro < 24; ro++){
        int r = rbase + ro;
        float acc = sb[r];
        const float4* swr = (const float4*)&sw[r*48];
        #pragma unroll
        for (int c4 = 0; c4 < 12; c4++){
            float4 w = swr[c4];
            acc += w.x*xr[4*c4] + w.y*xr[4*c4+1] + w.z*xr[4*c4+2] + w.w*xr[4*c4+3];
        }
        sp[px_l*48 + scol + ro] = f2u(acc * scale);
    }
    __syncthreads();

    // coalesced copy-out: 3 tensors * 768 dwords each
    unsigned int* qd = (unsigned int*)q + p0*24;
    unsigned int* kd = (unsigned int*)k + p0*24;
    unsigned int* vd = (unsigned int*)v + p0*24;
    const unsigned int* src = (const unsigned int*)&sstage[0][0];
    for (int idx = tid; idx < 3*768; idx += 192){
        int tsr = idx / 768, d = idx - tsr*768;
        unsigned int val = src[idx];
        (tsr == 0 ? qd : tsr == 1 ? kd : vd)[d] = val;
    }
}

// ------------- Kernel 2: reduce partials -> ECA conv1d(k=7,pad=3) -> sigmoid ----
// 192 threads = 48 channels x 4 summers
__global__ __launch_bounds__(192) void gate_kernel(
    const float* __restrict__ chpart, const float* __restrict__ wts,
    float* __restrict__ gate)
{
    __shared__ float part[4][48];
    __shared__ float m[48];
    const int tid = threadIdx.x;
    const int c = tid % 48;
    const int s = tid / 48;            // 0..3
    float acc = 0.f;
    for (int b = s; b < NBLK1; b += 4)
        acc += chpart[b*48 + c];
    part[s][c] = acc;
    __syncthreads();
    if (tid < 48){
        m[tid] = (part[0][tid] + part[1][tid] + part[2][tid] + part[3][tid])
                 * (1.f / (float)HW_);
    }
    __syncthreads();
    if (tid < 48){
        float a = 0.f;
        for (int kk = 0; kk < 7; kk++){
            int cc = tid + kk - 3;
            if (cc >= 0 && cc < 48) a += wts[O_ECA + kk] * m[cc];
        }
        gate[tid] = 1.f / (1.f + expf(-a));
    }
}

// ------------- Kernel 3: neighborhood attention (K=7, DIL=3), bf16 gathers ------
// grid (HW/128, 2 heads), block 256: 2 lanes per (px); each lane handles 12 ch.
__global__ __launch_bounds__(256) void attn_kernel(
    const ushort_t* __restrict__ q, const ushort_t* __restrict__ k,
    const ushort_t* __restrict__ v, const float* __restrict__ wts,
    float* __restrict__ aout)
{
    const int head = blockIdx.y;
    __shared__ float srpb[169];
    for (int i = threadIdx.x; i < 169; i += 256) srpb[i] = wts[O_RPB + head*169 + i];
    __syncthreads();

    const int tid  = threadIdx.x;
    const int px   = blockIdx.x * 128 + (tid >> 1);
    const int half = tid & 1;
    const int i = px / Wd, j = px % Wd;
    const int sti = wstart(i), stj = wstart(j);
    const int pbi = (sti - i) / 3 + 6;
    const int pbj = (stj - j) / 3 + 6;
    const int choff = head*24 + half*12;

    float qr[12];
    {
        const ushort4* qp = (const ushort4*)(q + px*48 + choff);
        #pragma unroll
        for (int b = 0; b < 3; b++){
            ushort4 uu = qp[b];
            qr[4*b]   = u2f(uu.x); qr[4*b+1] = u2f(uu.y);
            qr[4*b+2] = u2f(uu.z); qr[4*b+3] = u2f(uu.w);
        }
    }

    float l[49];
    float mx = -1e30f;
    #pragma unroll
    for (int xx = 0; xx < 7; xx++){
        int ii = sti + 3*xx;
        #pragma unroll
        for (int yy = 0; yy < 7; yy++){
            int jj = stj + 3*yy;
            const ushort4* kp = (const ushort4*)(k + (ii*Wd + jj)*48 + choff);
            float acc = 0.f;
            #pragma unroll
            for (int b = 0; b < 3; b++){
                ushort4 uu = kp[b];
                acc += qr[4*b]*u2f(uu.x) + qr[4*b+1]*u2f(uu.y)
                     + qr[4*b+2]*u2f(uu.z) + qr[4*b+3]*u2f(uu.w);
            }
            acc += __shfl_xor(acc, 1);               // combine channel halves
            acc += srpb[(pbi+xx)*13 + (pbj+yy)];
            l[xx*7+yy] = acc;
            mx = fmaxf(mx, acc);
        }
    }
    float s = 0.f;
    #pragma unroll
    for (int t = 0; t < 49; t++){ l[t] = __expf(l[t]-mx); s += l[t]; }
    float inv = 1.f / s;

    float acc[12];
    #pragma unroll
    for (int c = 0; c < 12; c++) acc[c] = 0.f;
    #pragma unroll
    for (int xx = 0; xx < 7; xx++){
        int ii = sti + 3*xx;
        #pragma unroll
        for (int yy = 0; yy < 7; yy++){
            const ushort4* vp = (const ushort4*)(v + (ii*Wd + stj + 3*yy)*48 + choff);
            float wgt = l[xx*7+yy] * inv;
            #pragma unroll
            for (int b = 0; b < 3; b++){
                ushort4 uu = vp[b];
                acc[4*b]   += wgt*u2f(uu.x); acc[4*b+1] += wgt*u2f(uu.y);
                acc[4*b+2] += wgt*u2f(uu.z); acc[4*b+3] += wgt*u2f(uu.w);
            }
        }
    }
    // planar fp32 out, coalesced (even lanes ch c, odd lanes ch 12+c)
    #pragma unroll
    for (int c = 0; c < 12; c++)
        aout[(choff + c)*HW_ + px] = acc[c];
}

// ------------- Kernel 4: proj + gate + residual (x2 = x + proj(aout)*gate) ------
// block 256 = 64 px * 4 wave-uniform o-groups (12 outputs each)
__global__ __launch_bounds__(256) void proj_kernel(
    const float* __restrict__ aout, const float* __restrict__ wts,
    const float* __restrict__ gate, const void* __restrict__ x,
    const int* __restrict__ mode, float* __restrict__ x2)
{
    __shared__ float sw[48*48];
    __shared__ float sbias[48];
    __shared__ float sg[48];
    const int tid = threadIdx.x;
    for (int i = tid; i < 2304; i += 256) sw[i] = wts[O_PROJW + i];
    if (tid < 48){
        sbias[tid] = wts[O_PROJB + tid];
        sg[tid]    = gate[tid];
    }
    __syncthreads();

    const int px = blockIdx.x * 64 + (tid & 63);
    const int og = tid >> 6;          // 0..3, wave-uniform
    const int ob = og * 12;

    float ar[48];
    #pragma unroll
    for (int c = 0; c < 48; c++) ar[c] = aout[c*HW_ + px];

    const float* xf = (const float*)x;
    const __hip_bfloat16* xb = (const __hip_bfloat16*)x;
    const int md = mode[0];
    #pragma unroll 2
    for (int oo = 0; oo < 12; oo++){
        int o = ob + oo;
        float acc = sbias[o];
        const float4* swr = (const float4*)&sw[o*48];
        #pragma unroll
        for (int c4 = 0; c4 < 12; c4++){
            float4 w = swr[c4];
            acc += w.x*ar[4*c4] + w.y*ar[4*c4+1] + w.z*ar[4*c4+2] + w.w*ar[4*c4+3];
        }
        float res = md ? xf[o*HW_ + px] : b2f(xb[o*HW_ + px]);
        x2[o*HW_ + px] = res + acc * sg[o];
    }
}

// ------------- Kernel 5: LN2 (inline) + pointwise1 (48 -> 254), bf16 out --------
__global__ __launch_bounds__(128) void pw1_kernel(
    const float* __restrict__ x2, const float* __restrict__ wts,
    ushort_t* __restrict__ t)
{
    int ob   = blockIdx.y * 64;
    int ocnt = min(64, 254 - ob);
    __shared__ float sw[64*48];
    __shared__ float sln[96];
    for (int i = threadIdx.x; i < ocnt*48; i += 128) sw[i] = wts[O_WIN + ob*48 + i];
    for (int i = threadIdx.x; i < 96;      i += 128) sln[i] = wts[O_LN2W + i];
    __syncthreads();

    int p = blockIdx.x * 128 + threadIdx.x;
    float xr[48];
    float mu = 0.f;
    #pragma unroll
    for (int c = 0; c < 48; c++){ xr[c] = x2[c*HW_ + p]; mu += xr[c]; }
    mu *= (1.f/48.f);
    float var = 0.f;
    #pragma unroll
    for (int c = 0; c < 48; c++){ float d = xr[c]-mu; var += d*d; }
    var *= (1.f/48.f);
    float rs = rsqrtf(var + 1e-5f);
    #pragma unroll
    for (int c = 0; c < 48; c++) xr[c] = (xr[c]-mu)*rs*sln[c] + sln[48+c];

    for (int o = 0; o < ocnt; o++){
        float acc = 0.f;
        const float4* swr = (const float4*)&sw[o*48];
        #pragma unroll
        for (int c4 = 0; c4 < 12; c4++){
            float4 w = swr[c4];
            acc += w.x*xr[4*c4] + w.y*xr[4*c4+1] + w.z*xr[4*c4+2] + w.w*xr[4*c4+3];
        }
        t[(ob+o)*HW_ + p] = f2u(acc);
    }
}

// ------------- Kernel 6: depthwise 3x3 + exact GeLU gating, bf16 in/out ---------
__global__ __launch_bounds__(256) void dw_kernel(
    const ushort_t* __restrict__ t, const float* __restrict__ wts,
    ushort_t* __restrict__ g)
{
    int ch = blockIdx.y;               // 0..126
    int p  = blockIdx.x * 256 + threadIdx.x;
    int i  = p / Wd, j = p % Wd;
    float w1[9], w2[9];
    #pragma unroll
    for (int s = 0; s < 9; s++){
        w1[s] = wts[O_WDW + ch*9 + s];
        w2[s] = wts[O_WDW + (ch+HIDc)*9 + s];
    }
    const ushort_t* t1 = t + (size_t)ch * HW_;
    const ushort_t* t2 = t + (size_t)(ch+HIDc) * HW_;
    float a1 = 0.f, a2 = 0.f;
    #pragma unroll
    for (int di = 0; di < 3; di++){
        int ii = i + di - 1;
        if (ii < 0 || ii >= 192) continue;
        #pragma unroll
        for (int dj = 0; dj < 3; dj++){
            int jj = j + dj - 1;
            if (jj < 0 || jj >= 192) continue;
            int off = ii*Wd + jj;
            a1 += w1[di*3+dj]*u2f(t1[off]);
            a2 += w2[di*3+dj]*u2f(t2[off]);
        }
    }
    float ge = a1 * 0.5f * (1.f + erff(a1 * 0.70710678118654752f)); // exact gelu
    g[(size_t)ch*HW_ + p] = f2u(ge * a2);
}

// ------------- Kernel 7: pointwise2 (127 -> 24x2) + final residual --------------
__global__ __launch_bounds__(128) void pw2_kernel(
    const ushort_t* __restrict__ g, const float* __restrict__ wts,
    const float* __restrict__ x2, void* __restrict__ outv,
    const int* __restrict__ mode)
{
    int ob = blockIdx.y * 24;          // 2 chunks of 24 output channels
    __shared__ float sw[24*127];
    for (int i = threadIdx.x; i < 24*127; i += 128) sw[i] = wts[O_WOUT + ob*127 + i];
    __syncthreads();

    int p = blockIdx.x * 128 + threadIdx.x;
    float acc[24];
    #pragma unroll
    for (int o = 0; o < 24; o++) acc[o] = 0.f;
    for (int c = 0; c < 127; c++){
        float gv = u2f(g[(size_t)c*HW_ + p]);
        #pragma unroll
        for (int o = 0; o < 24; o++) acc[o] += sw[o*127+c]*gv;
    }
    if (mode[0]){
        float* out = (float*)outv;
        #pragma unroll
        for (int o = 0; o < 24; o++){
            int oc = ob + o;
            out[(size_t)oc*HW_ + p] = x2[(size_t)oc*HW_ + p] + acc[o];
        }
    } else {
        __hip_bfloat16* out = (__hip_bfloat16*)outv;
        #pragma unroll
        for (int o = 0; o < 24; o++){
            int oc = ob + o;
            out[(size_t)oc*HW_ + p] =
                __float2bfloat16(x2[(size_t)oc*HW_ + p] + acc[o]);
        }
    }
}

extern "C" void kernel_launch(void* const* d_in, const int* in_sizes, int n_in,
                              void* d_out, int out_size, void* d_ws, size_t ws_size,
                              hipStream_t stream)
{
    (void)in_sizes; (void)n_in; (void)out_size;

    char* ws = (char*)d_ws;
    // region R (aliased): t bf16 [254][HW] = 18,726,912 B; inside it live
    //   q,k,v bf16 [HW][48] (3,538,944 B each) + aout fp32 [48][HW] (7,077,888 B)
    ushort_t* q    = (ushort_t*)(ws);
    ushort_t* k    = (ushort_t*)(ws + 3538944);
    ushort_t* v    = (ushort_t*)(ws + 7077888);
    float*    aout = (float*)   (ws + 10616832);
    ushort_t* t    = (ushort_t*)(ws);
    float*    x2   = (float*)   (ws + 18726912);
    ushort_t* g    = (ushort_t*)(ws + 25804800);
    float*    gate = (float*)   (ws + 35168448);
    int*      mode = (int*)     (ws + 35168640);
    float*    wts  = (float*)   (ws + 35168656);
    float*    chpart=(float*)   (ws + 35168656 + (size_t)WTS_LEN*4); // [NBLK1][48]

    size_t need = 35168656 + (size_t)WTS_LEN*4 + (size_t)NBLK1*48*4;
    if (ws_size < need) return;

    detect_kernel<<<1, 256, 0, stream>>>((const ushort_t*)d_in[0], mode);
    convert_kernel<<<13, 256, 0, stream>>>(
        d_in[1], d_in[2], d_in[3], d_in[4], d_in[5], d_in[6], d_in[7],
        d_in[8], d_in[9], d_in[10], d_in[11], d_in[12], d_in[13], mode, wts);

    ln1qkv_kernel<<<dim3(NBLK1), 192, 0, stream>>>(d_in[0], mode, wts,
                                                   q, k, v, chpart);
    gate_kernel<<<1, 192, 0, stream>>>(chpart, wts, gate);
    attn_kernel<<<dim3(HW_/128, 2), 256, 0, stream>>>(q, k, v, wts, aout);
    proj_kernel<<<dim3(HW_/64), 256, 0, stream>>>(aout, wts, gate, d_in[0],
                                                  mode, x2);
    pw1_kernel<<<dim3(HW_/128, 4), 128, 0, stream>>>(x2, wts, t);
    dw_kernel<<<dim3(HW_/256, 127), 256, 0, stream>>>(t, wts, g);
    pw2_kernel<<<dim3(HW_/128, 2), 128, 0, stream>>>(g, wts, x2, d_out, mode);
}

// Round 5
// 315.166 us; speedup vs baseline: 2.2055x; 1.2043x over previous
//
#include <hip/hip_runtime.h>
#include <hip/hip_bf16.h>
#include <math.h>

#define HW_ (192*192)
#define Wd 192
#define HIDc 127
#define NBLK1 (HW_/32)   // 1152 ln1qkv blocks

// fp32 weight-copy offsets inside ws "wts" region
#define O_LN1W 0
#define O_QKVW 96
#define O_QKVB 7008
#define O_RPB  7152
#define O_PROJW 7490
#define O_PROJB 9794
#define O_ECA  9842
#define O_LN2W 9849
#define O_WIN  9945
#define O_WDW  22137
#define O_WOUT 24423
#define WTS_LEN 30519

typedef unsigned short ushort_t;

__device__ __forceinline__ float b2f(__hip_bfloat16 v){ return __bfloat162float(v); }
__device__ __forceinline__ float u2f(ushort_t h){ return __uint_as_float(((unsigned)h)<<16); }
__device__ __forceinline__ ushort_t f2u(float f){
    __hip_bfloat16 h = __float2bfloat16(f);
    union { __hip_bfloat16 b; ushort_t u; } c; c.b = h; return c.u;
}

__device__ __forceinline__ int wstart(int i){
    // L=192, K=7, DIL=3 closed form of _window_starts
    if (i < 9) return i % 3;
    if (i >= 183) return 171 + (i % 3);
    return i - 9;
}

// ------------- Kernel A: detect input dtype (bf16 vs fp32) ----------------------
__global__ void detect_kernel(const ushort_t* __restrict__ xu, int* __restrict__ mode)
{
    __shared__ int sbad;
    if (threadIdx.x == 0) sbad = 0;
    __syncthreads();
    int bad = 0;
    for (int t = threadIdx.x; t < 16384; t += 256){
        unsigned int u = xu[2*t];
        float f = __uint_as_float(u << 16);
        if (!(fabsf(f) < 100.f)) bad++;
    }
    atomicAdd(&sbad, bad);
    __syncthreads();
    if (threadIdx.x == 0) mode[0] = (sbad > 1000) ? 1 : 0;
}

// ------------- Kernel B: convert all weight tensors to fp32 in ws ---------------
__global__ void convert_kernel(
    const void* p0, const void* p1, const void* p2, const void* p3,
    const void* p4, const void* p5, const void* p6, const void* p7,
    const void* p8, const void* p9, const void* p10, const void* p11,
    const void* p12, const int* __restrict__ mode, float* __restrict__ wts)
{
    const void* ps[13] = {p0,p1,p2,p3,p4,p5,p6,p7,p8,p9,p10,p11,p12};
    const int sz[13]  = {48,48,6912,144,338,2304,48,7,48,48,12192,2286,6096};
    const int off[13] = {O_LN1W,48,O_QKVW,O_QKVB,O_RPB,O_PROJW,O_PROJB,O_ECA,
                         O_LN2W,9897,O_WIN,O_WDW,O_WOUT};
    int b = blockIdx.x;
    int n = sz[b];
    float* dst = wts + off[b];
    if (mode[0]){
        const float* s = (const float*)ps[b];
        for (int i = threadIdx.x; i < n; i += 256) dst[i] = s[i];
    } else {
        const __hip_bfloat16* s = (const __hip_bfloat16*)ps[b];
        for (int i = threadIdx.x; i < n; i += 256) dst[i] = b2f(s[i]);
    }
}

// ------------- Kernel 1: LN1 + QKV proj (6 thr/px) + ECA partial sums -----------
// block: 192 thr = 32 px * 6 r-groups (24 outputs each). q/k/v out = bf16 [p][48].
__global__ __launch_bounds__(192) void ln1qkv_kernel(
    const void* __restrict__ x, const int* __restrict__ mode,
    const float* __restrict__ wts,
    ushort_t* __restrict__ q, ushort_t* __restrict__ k, ushort_t* __restrict__ v,
    float* __restrict__ chpart)
{
    __shared__ float sw[144*48];          // 27648 B
    __shared__ float sx[32*49];           // 6272 B (pad 49)
    __shared__ float sb[144];
    __shared__ float sln[96];
    __shared__ ushort_t sstage[3][32*48]; // 9216 B

    const int tid = threadIdx.x;
    const int px_l = tid & 31;
    const int r6   = tid >> 5;            // 0..5, wave-uniform in pairs
    const int p0   = blockIdx.x * 32;

    for (int i = tid; i < 144*48; i += 192) sw[i] = wts[O_QKVW + i];
    for (int i = tid; i < 144;    i += 192) sb[i] = wts[O_QKVB + i];
    for (int i = tid; i < 96;     i += 192) sln[i] = wts[O_LN1W + i];

    // x tile load, planar-coalesced
    if (mode[0]){
        const float* xf = (const float*)x;
        for (int idx = tid; idx < 32*48; idx += 192){
            int c = idx >> 5, pl = idx & 31;
            sx[pl*49 + c] = xf[c*HW_ + p0 + pl];
        }
    } else {
        const __hip_bfloat16* xb = (const __hip_bfloat16*)x;
        for (int idx = tid; idx < 32*48; idx += 192){
            int c = idx >> 5, pl = idx & 31;
            sx[pl*49 + c] = b2f(xb[c*HW_ + p0 + pl]);
        }
    }
    __syncthreads();

    float xr[48];
    float mu = 0.f;
    #pragma unroll
    for (int c = 0; c < 48; c++){ xr[c] = sx[px_l*49 + c]; mu += xr[c]; }
    mu *= (1.f/48.f);
    float var = 0.f;
    #pragma unroll
    for (int c = 0; c < 48; c++){ float d = xr[c]-mu; var += d*d; }
    var *= (1.f/48.f);
    float rs = rsqrtf(var + 1e-5f);
    #pragma unroll
    for (int c = 0; c < 48; c++) xr[c] = (xr[c]-mu)*rs*sln[c] + sln[48+c];

    // ECA per-block partials: wave 0 (lanes 0..31 = px r6=0, 32..63 same px r6=1)
    if (tid < 64){
        #pragma unroll
        for (int c = 0; c < 48; c++){
            float s = xr[c];
            s += __shfl_xor(s, 1);  s += __shfl_xor(s, 2);  s += __shfl_xor(s, 4);
            s += __shfl_xor(s, 8);  s += __shfl_xor(s, 16); s += __shfl_xor(s, 32);
            if (tid == 0) chpart[blockIdx.x*48 + c] = s * 0.5f;  // halves double-count
        }
    }

    const int rbase = r6 * 24;
    const float scale = (r6 < 2) ? 0.20412414523193154f : 1.0f;
    ushort_t* sp = sstage[r6 >> 1];
    const int scol = (r6 & 1) * 24;
    #pragma unroll 4
    for (int ro = 0; ro < 24; ro++){
        int r = rbase + ro;
        float acc = sb[r];
        const float4* swr = (const float4*)&sw[r*48];
        #pragma unroll
        for (int c4 = 0; c4 < 12; c4++){
            float4 w = swr[c4];
            acc += w.x*xr[4*c4] + w.y*xr[4*c4+1] + w.z*xr[4*c4+2] + w.w*xr[4*c4+3];
        }
        sp[px_l*48 + scol + ro] = f2u(acc * scale);
    }
    __syncthreads();

    // coalesced copy-out: 3 tensors * 768 dwords each
    unsigned int* qd = (unsigned int*)q + p0*24;
    unsigned int* kd = (unsigned int*)k + p0*24;
    unsigned int* vd = (unsigned int*)v + p0*24;
    const unsigned int* src = (const unsigned int*)&sstage[0][0];
    for (int idx = tid; idx < 3*768; idx += 192){
        int tsr = idx / 768, d = idx - tsr*768;
        unsigned int val = src[idx];
        (tsr == 0 ? qd : tsr == 1 ? kd : vd)[d] = val;
    }
}

// ------------- Kernel 2a: parallel partial reduction (48 blocks, 1 per channel) -
__global__ __launch_bounds__(256) void gatered_kernel(
    const float* __restrict__ chpart, float* __restrict__ msum)
{
    __shared__ float red[4];
    const int c = blockIdx.x;          // channel
    const int tid = threadIdx.x;
    float acc = 0.f;
    for (int b = tid; b < NBLK1; b += 256)
        acc += chpart[b*48 + c];
    acc += __shfl_xor(acc, 1);  acc += __shfl_xor(acc, 2);  acc += __shfl_xor(acc, 4);
    acc += __shfl_xor(acc, 8);  acc += __shfl_xor(acc, 16); acc += __shfl_xor(acc, 32);
    if ((tid & 63) == 0) red[tid >> 6] = acc;
    __syncthreads();
    if (tid == 0)
        msum[c] = (red[0] + red[1] + red[2] + red[3]) * (1.f / (float)HW_);
}

// ------------- Kernel 2b: ECA conv1d(k=7,pad=3) -> sigmoid ----------------------
__global__ void gate_kernel(const float* __restrict__ msum,
                            const float* __restrict__ wts,
                            float* __restrict__ gate)
{
    __shared__ float m[48];
    int t = threadIdx.x;
    if (t < 48) m[t] = msum[t];
    __syncthreads();
    if (t < 48){
        float a = 0.f;
        for (int kk = 0; kk < 7; kk++){
            int cc = t + kk - 3;
            if (cc >= 0 && cc < 48) a += wts[O_ECA + kk] * m[cc];
        }
        gate[t] = 1.f / (1.f + expf(-a));
    }
}

// ------------- Kernel 3: neighborhood attention (K=7, DIL=3), bf16 gathers ------
// grid (HW/128, 2 heads), block 256: 2 lanes per (px); each lane handles 12 ch.
__global__ __launch_bounds__(256) void attn_kernel(
    const ushort_t* __restrict__ q, const ushort_t* __restrict__ k,
    const ushort_t* __restrict__ v, const float* __restrict__ wts,
    float* __restrict__ aout)
{
    const int head = blockIdx.y;
    __shared__ float srpb[169];
    for (int i = threadIdx.x; i < 169; i += 256) srpb[i] = wts[O_RPB + head*169 + i];
    __syncthreads();

    const int tid  = threadIdx.x;
    const int px   = blockIdx.x * 128 + (tid >> 1);
    const int half = tid & 1;
    const int i = px / Wd, j = px % Wd;
    const int sti = wstart(i), stj = wstart(j);
    const int pbi = (sti - i) / 3 + 6;
    const int pbj = (stj - j) / 3 + 6;
    const int choff = head*24 + half*12;

    float qr[12];
    {
        const ushort4* qp = (const ushort4*)(q + px*48 + choff);
        #pragma unroll
        for (int b = 0; b < 3; b++){
            ushort4 uu = qp[b];
            qr[4*b]   = u2f(uu.x); qr[4*b+1] = u2f(uu.y);
            qr[4*b+2] = u2f(uu.z); qr[4*b+3] = u2f(uu.w);
        }
    }

    float l[49];
    float mx = -1e30f;
    #pragma unroll
    for (int xx = 0; xx < 7; xx++){
        int ii = sti + 3*xx;
        #pragma unroll
        for (int yy = 0; yy < 7; yy++){
            int jj = stj + 3*yy;
            const ushort4* kp = (const ushort4*)(k + (ii*Wd + jj)*48 + choff);
            float acc = 0.f;
            #pragma unroll
            for (int b = 0; b < 3; b++){
                ushort4 uu = kp[b];
                acc += qr[4*b]*u2f(uu.x) + qr[4*b+1]*u2f(uu.y)
                     + qr[4*b+2]*u2f(uu.z) + qr[4*b+3]*u2f(uu.w);
            }
            acc += __shfl_xor(acc, 1);               // combine channel halves
            acc += srpb[(pbi+xx)*13 + (pbj+yy)];
            l[xx*7+yy] = acc;
            mx = fmaxf(mx, acc);
        }
    }
    float s = 0.f;
    #pragma unroll
    for (int t = 0; t < 49; t++){ l[t] = __expf(l[t]-mx); s += l[t]; }
    float inv = 1.f / s;

    float acc[12];
    #pragma unroll
    for (int c = 0; c < 12; c++) acc[c] = 0.f;
    #pragma unroll
    for (int xx = 0; xx < 7; xx++){
        int ii = sti + 3*xx;
        #pragma unroll
        for (int yy = 0; yy < 7; yy++){
            const ushort4* vp = (const ushort4*)(v + (ii*Wd + stj + 3*yy)*48 + choff);
            float wgt = l[xx*7+yy] * inv;
            #pragma unroll
            for (int b = 0; b < 3; b++){
                ushort4 uu = vp[b];
                acc[4*b]   += wgt*u2f(uu.x); acc[4*b+1] += wgt*u2f(uu.y);
                acc[4*b+2] += wgt*u2f(uu.z); acc[4*b+3] += wgt*u2f(uu.w);
            }
        }
    }
    // planar fp32 out, coalesced (even lanes ch c, odd lanes ch 12+c)
    #pragma unroll
    for (int c = 0; c < 12; c++)
        aout[(choff + c)*HW_ + px] = acc[c];
}

// ------------- Kernel 4: proj + gate + residual (x2 = x + proj(aout)*gate) ------
// block 256 = 64 px * 4 wave-uniform o-groups (12 outputs each)
__global__ __launch_bounds__(256) void proj_kernel(
    const float* __restrict__ aout, const float* __restrict__ wts,
    const float* __restrict__ gate, const void* __restrict__ x,
    const int* __restrict__ mode, float* __restrict__ x2)
{
    __shared__ float sw[48*48];
    __shared__ float sbias[48];
    __shared__ float sg[48];
    const int tid = threadIdx.x;
    for (int i = tid; i < 2304; i += 256) sw[i] = wts[O_PROJW + i];
    if (tid < 48){
        sbias[tid] = wts[O_PROJB + tid];
        sg[tid]    = gate[tid];
    }
    __syncthreads();

    const int px = blockIdx.x * 64 + (tid & 63);
    const int og = tid >> 6;          // 0..3, wave-uniform
    const int ob = og * 12;

    float ar[48];
    #pragma unroll
    for (int c = 0; c < 48; c++) ar[c] = aout[c*HW_ + px];

    const float* xf = (const float*)x;
    const __hip_bfloat16* xb = (const __hip_bfloat16*)x;
    const int md = mode[0];
    #pragma unroll 2
    for (int oo = 0; oo < 12; oo++){
        int o = ob + oo;
        float acc = sbias[o];
        const float4* swr = (const float4*)&sw[o*48];
        #pragma unroll
        for (int c4 = 0; c4 < 12; c4++){
            float4 w = swr[c4];
            acc += w.x*ar[4*c4] + w.y*ar[4*c4+1] + w.z*ar[4*c4+2] + w.w*ar[4*c4+3];
        }
        float res = md ? xf[o*HW_ + px] : b2f(xb[o*HW_ + px]);
        x2[o*HW_ + px] = res + acc * sg[o];
    }
}

// ------------- Kernel 5: LN2 (inline) + pointwise1 (48 -> 254), bf16 out --------
__global__ __launch_bounds__(128) void pw1_kernel(
    const float* __restrict__ x2, const float* __restrict__ wts,
    ushort_t* __restrict__ t)
{
    int ob   = blockIdx.y * 64;
    int ocnt = min(64, 254 - ob);
    __shared__ float sw[64*48];
    __shared__ float sln[96];
    for (int i = threadIdx.x; i < ocnt*48; i += 128) sw[i] = wts[O_WIN + ob*48 + i];
    for (int i = threadIdx.x; i < 96;      i += 128) sln[i] = wts[O_LN2W + i];
    __syncthreads();

    int p = blockIdx.x * 128 + threadIdx.x;
    float xr[48];
    float mu = 0.f;
    #pragma unroll
    for (int c = 0; c < 48; c++){ xr[c] = x2[c*HW_ + p]; mu += xr[c]; }
    mu *= (1.f/48.f);
    float var = 0.f;
    #pragma unroll
    for (int c = 0; c < 48; c++){ float d = xr[c]-mu; var += d*d; }
    var *= (1.f/48.f);
    float rs = rsqrtf(var + 1e-5f);
    #pragma unroll
    for (int c = 0; c < 48; c++) xr[c] = (xr[c]-mu)*rs*sln[c] + sln[48+c];

    for (int o = 0; o < ocnt; o++){
        float acc = 0.f;
        const float4* swr = (const float4*)&sw[o*48];
        #pragma unroll
        for (int c4 = 0; c4 < 12; c4++){
            float4 w = swr[c4];
            acc += w.x*xr[4*c4] + w.y*xr[4*c4+1] + w.z*xr[4*c4+2] + w.w*xr[4*c4+3];
        }
        t[(ob+o)*HW_ + p] = f2u(acc);
    }
}

// ------------- Kernel 6: depthwise 3x3 + exact GeLU gating, bf16 in/out ---------
__global__ __launch_bounds__(256) void dw_kernel(
    const ushort_t* __restrict__ t, const float* __restrict__ wts,
    ushort_t* __restrict__ g)
{
    int ch = blockIdx.y;               // 0..126
    int p  = blockIdx.x * 256 + threadIdx.x;
    int i  = p / Wd, j = p % Wd;
    float w1[9], w2[9];
    #pragma unroll
    for (int s = 0; s < 9; s++){
        w1[s] = wts[O_WDW + ch*9 + s];
        w2[s] = wts[O_WDW + (ch+HIDc)*9 + s];
    }
    const ushort_t* t1 = t + (size_t)ch * HW_;
    const ushort_t* t2 = t + (size_t)(ch+HIDc) * HW_;
    float a1 = 0.f, a2 = 0.f;
    #pragma unroll
    for (int di = 0; di < 3; di++){
        int ii = i + di - 1;
        if (ii < 0 || ii >= 192) continue;
        #pragma unroll
        for (int dj = 0; dj < 3; dj++){
            int jj = j + dj - 1;
            if (jj < 0 || jj >= 192) continue;
            int off = ii*Wd + jj;
            a1 += w1[di*3+dj]*u2f(t1[off]);
            a2 += w2[di*3+dj]*u2f(t2[off]);
        }
    }
    float ge = a1 * 0.5f * (1.f + erff(a1 * 0.70710678118654752f)); // exact gelu
    g[(size_t)ch*HW_ + p] = f2u(ge * a2);
}

// ------------- Kernel 7: pointwise2 (127 -> 24x2) + final residual --------------
__global__ __launch_bounds__(128) void pw2_kernel(
    const ushort_t* __restrict__ g, const float* __restrict__ wts,
    const float* __restrict__ x2, void* __restrict__ outv,
    const int* __restrict__ mode)
{
    int ob = blockIdx.y * 24;          // 2 chunks of 24 output channels
    __shared__ float sw[24*127];
    for (int i = threadIdx.x; i < 24*127; i += 128) sw[i] = wts[O_WOUT + ob*127 + i];
    __syncthreads();

    int p = blockIdx.x * 128 + threadIdx.x;
    float acc[24];
    #pragma unroll
    for (int o = 0; o < 24; o++) acc[o] = 0.f;
    for (int c = 0; c < 127; c++){
        float gv = u2f(g[(size_t)c*HW_ + p]);
        #pragma unroll
        for (int o = 0; o < 24; o++) acc[o] += sw[o*127+c]*gv;
    }
    if (mode[0]){
        float* out = (float*)outv;
        #pragma unroll
        for (int o = 0; o < 24; o++){
            int oc = ob + o;
            out[(size_t)oc*HW_ + p] = x2[(size_t)oc*HW_ + p] + acc[o];
        }
    } else {
        __hip_bfloat16* out = (__hip_bfloat16*)outv;
        #pragma unroll
        for (int o = 0; o < 24; o++){
            int oc = ob + o;
            out[(size_t)oc*HW_ + p] =
                __float2bfloat16(x2[(size_t)oc*HW_ + p] + acc[o]);
        }
    }
}

extern "C" void kernel_launch(void* const* d_in, const int* in_sizes, int n_in,
                              void* d_out, int out_size, void* d_ws, size_t ws_size,
                              hipStream_t stream)
{
    (void)in_sizes; (void)n_in; (void)out_size;

    char* ws = (char*)d_ws;
    // region R (aliased): t bf16 [254][HW] = 18,726,912 B; inside it live
    //   q,k,v bf16 [HW][48] (3,538,944 B each) + aout fp32 [48][HW] (7,077,888 B)
    ushort_t* q    = (ushort_t*)(ws);
    ushort_t* k    = (ushort_t*)(ws + 3538944);
    ushort_t* v    = (ushort_t*)(ws + 7077888);
    float*    aout = (float*)   (ws + 10616832);
    ushort_t* t    = (ushort_t*)(ws);
    float*    x2   = (float*)   (ws + 18726912);
    ushort_t* g    = (ushort_t*)(ws + 25804800);
    float*    gate = (float*)   (ws + 35168448);
    int*      mode = (int*)     (ws + 35168640);
    float*    wts  = (float*)   (ws + 35168656);
    float*    chpart=(float*)   (ws + 35168656 + (size_t)WTS_LEN*4); // [NBLK1][48]
    float*    msum = chpart + (size_t)NBLK1*48;                      // [48]

    size_t need = 35168656 + (size_t)WTS_LEN*4 + (size_t)NBLK1*48*4 + 48*4;
    if (ws_size < need) return;

    detect_kernel<<<1, 256, 0, stream>>>((const ushort_t*)d_in[0], mode);
    convert_kernel<<<13, 256, 0, stream>>>(
        d_in[1], d_in[2], d_in[3], d_in[4], d_in[5], d_in[6], d_in[7],
        d_in[8], d_in[9], d_in[10], d_in[11], d_in[12], d_in[13], mode, wts);

    ln1qkv_kernel<<<dim3(NBLK1), 192, 0, stream>>>(d_in[0], mode, wts,
                                                   q, k, v, chpart);
    gatered_kernel<<<48, 256, 0, stream>>>(chpart, msum);
    gate_kernel<<<1, 64, 0, stream>>>(msum, wts, gate);
    attn_kernel<<<dim3(HW_/128, 2), 256, 0, stream>>>(q, k, v, wts, aout);
    proj_kernel<<<dim3(HW_/64), 256, 0, stream>>>(aout, wts, gate, d_in[0],
                                                  mode, x2);
    pw1_kernel<<<dim3(HW_/128, 4), 128, 0, stream>>>(x2, wts, t);
    dw_kernel<<<dim3(HW_/256, 127), 256, 0, stream>>>(t, wts, g);
    pw2_kernel<<<dim3(HW_/128, 2), 128, 0, stream>>>(g, wts, x2, d_out, mode);
}

// Round 6
// 298.204 us; speedup vs baseline: 2.3309x; 1.0569x over previous
//
#include <hip/hip_runtime.h>
#include <hip/hip_bf16.h>
#include <math.h>

#define HW_ (192*192)
#define Wd 192
#define HIDc 127
#define NBLK1 (HW_/32)   // 1152 ln1qkv blocks

// fp32 weight-copy offsets inside ws "wts" region
#define O_LN1W 0
#define O_QKVW 96
#define O_QKVB 7008
#define O_RPB  7152
#define O_PROJW 7490
#define O_PROJB 9794
#define O_ECA  9842
#define O_LN2W 9849
#define O_WIN  9945
#define O_WDW  22137
#define O_WOUT 24423
#define WTS_LEN 30519

typedef unsigned short ushort_t;

__device__ __forceinline__ float b2f(__hip_bfloat16 v){ return __bfloat162float(v); }
__device__ __forceinline__ float u2f(ushort_t h){ return __uint_as_float(((unsigned)h)<<16); }
__device__ __forceinline__ ushort_t f2u(float f){
    __hip_bfloat16 h = __float2bfloat16(f);
    union { __hip_bfloat16 b; ushort_t u; } c; c.b = h; return c.u;
}

__device__ __forceinline__ int wstart(int i){
    // L=192, K=7, DIL=3 closed form of _window_starts
    if (i < 9) return i % 3;
    if (i >= 183) return 171 + (i % 3);
    return i - 9;
}

// ------------- Kernel A: detect input dtype (bf16 vs fp32) ----------------------
__global__ void detect_kernel(const ushort_t* __restrict__ xu, int* __restrict__ mode)
{
    __shared__ int sbad;
    if (threadIdx.x == 0) sbad = 0;
    __syncthreads();
    int bad = 0;
    for (int t = threadIdx.x; t < 16384; t += 256){
        unsigned int u = xu[2*t];
        float f = __uint_as_float(u << 16);
        if (!(fabsf(f) < 100.f)) bad++;
    }
    atomicAdd(&sbad, bad);
    __syncthreads();
    if (threadIdx.x == 0) mode[0] = (sbad > 1000) ? 1 : 0;
}

// ------------- Kernel B: convert weights to fp32 (+ qkv bf16 copy) --------------
__global__ void convert_kernel(
    const void* p0, const void* p1, const void* p2, const void* p3,
    const void* p4, const void* p5, const void* p6, const void* p7,
    const void* p8, const void* p9, const void* p10, const void* p11,
    const void* p12, const int* __restrict__ mode, float* __restrict__ wts,
    ushort_t* __restrict__ qkvbf)
{
    const void* ps[13] = {p0,p1,p2,p3,p4,p5,p6,p7,p8,p9,p10,p11,p12};
    const int sz[13]  = {48,48,6912,144,338,2304,48,7,48,48,12192,2286,6096};
    const int off[13] = {O_LN1W,48,O_QKVW,O_QKVB,O_RPB,O_PROJW,O_PROJB,O_ECA,
                         O_LN2W,9897,O_WIN,O_WDW,O_WOUT};
    int b = blockIdx.x;
    if (b == 13){   // packed bf16 copy of qkv_w for ln1qkv LDS staging
        if (mode[0]){
            const float* s = (const float*)p2;
            for (int i = threadIdx.x; i < 6912; i += 256) qkvbf[i] = f2u(s[i]);
        } else {
            const ushort_t* s = (const ushort_t*)p2;
            for (int i = threadIdx.x; i < 6912; i += 256) qkvbf[i] = s[i];
        }
        return;
    }
    int n = sz[b];
    float* dst = wts + off[b];
    if (mode[0]){
        const float* s = (const float*)ps[b];
        for (int i = threadIdx.x; i < n; i += 256) dst[i] = s[i];
    } else {
        const __hip_bfloat16* s = (const __hip_bfloat16*)ps[b];
        for (int i = threadIdx.x; i < n; i += 256) dst[i] = b2f(s[i]);
    }
}

// ------------- Kernel 1: LN1 + QKV proj (6 thr/px) + ECA partial sums -----------
// block: 192 thr = 32 px * 6 r-groups (24 outputs each). q/k/v out = bf16 [p][48].
// Weights staged in LDS as bf16 (13.8 KB); direct packed global stores (no sstage).
// LDS ~21 KB -> 7 blocks/CU.
__global__ __launch_bounds__(192) void ln1qkv_kernel(
    const void* __restrict__ x, const int* __restrict__ mode,
    const float* __restrict__ wts, const ushort_t* __restrict__ qkvbf,
    ushort_t* __restrict__ q, ushort_t* __restrict__ k, ushort_t* __restrict__ v,
    float* __restrict__ chpart)
{
    __shared__ ushort_t ssw[144*48];      // 13824 B, bf16 weights
    __shared__ float sx[32*49];           // 6272 B (pad 49)
    __shared__ float sb[144];
    __shared__ float sln[96];

    const int tid = threadIdx.x;
    const int px_l = tid & 31;
    const int r6   = tid >> 5;            // 0..5, wave-uniform
    const int p0   = blockIdx.x * 32;
    const int p    = p0 + px_l;

    {   // weight stage: coalesced dword copy of 3456 dwords
        const unsigned int* srcw = (const unsigned int*)qkvbf;
        unsigned int* dstw = (unsigned int*)ssw;
        for (int i = tid; i < 3456; i += 192) dstw[i] = srcw[i];
    }
    for (int i = tid; i < 144; i += 192) sb[i] = wts[O_QKVB + i];
    for (int i = tid; i < 96;  i += 192) sln[i] = wts[O_LN1W + i];

    // x tile load, planar-coalesced
    if (mode[0]){
        const float* xf = (const float*)x;
        for (int idx = tid; idx < 32*48; idx += 192){
            int c = idx >> 5, pl = idx & 31;
            sx[pl*49 + c] = xf[c*HW_ + p0 + pl];
        }
    } else {
        const __hip_bfloat16* xb = (const __hip_bfloat16*)x;
        for (int idx = tid; idx < 32*48; idx += 192){
            int c = idx >> 5, pl = idx & 31;
            sx[pl*49 + c] = b2f(xb[c*HW_ + p0 + pl]);
        }
    }
    __syncthreads();

    float xr[48];
    float mu = 0.f;
    #pragma unroll
    for (int c = 0; c < 48; c++){ xr[c] = sx[px_l*49 + c]; mu += xr[c]; }
    mu *= (1.f/48.f);
    float var = 0.f;
    #pragma unroll
    for (int c = 0; c < 48; c++){ float d = xr[c]-mu; var += d*d; }
    var *= (1.f/48.f);
    float rs = rsqrtf(var + 1e-5f);
    #pragma unroll
    for (int c = 0; c < 48; c++) xr[c] = (xr[c]-mu)*rs*sln[c] + sln[48+c];

    // ECA per-block partials: wave 0 (lanes 0..31 = px r6=0, 32..63 same px r6=1)
    if (tid < 64){
        #pragma unroll
        for (int c = 0; c < 48; c++){
            float s = xr[c];
            s += __shfl_xor(s, 1);  s += __shfl_xor(s, 2);  s += __shfl_xor(s, 4);
            s += __shfl_xor(s, 8);  s += __shfl_xor(s, 16); s += __shfl_xor(s, 32);
            if (tid == 0) chpart[blockIdx.x*48 + c] = s * 0.5f;  // halves double-count
        }
    }

    const int rbase = r6 * 24;
    const float scale = (r6 < 2) ? 0.20412414523193154f : 1.0f;
    float ov[24];
    #pragma unroll 4
    for (int ro = 0; ro < 24; ro++){
        int r = rbase + ro;
        float acc = sb[r];
        const ushort4* wr = (const ushort4*)&ssw[r*48];
        #pragma unroll
        for (int c4 = 0; c4 < 12; c4++){
            ushort4 w = wr[c4];
            acc += u2f(w.x)*xr[4*c4]   + u2f(w.y)*xr[4*c4+1]
                 + u2f(w.z)*xr[4*c4+2] + u2f(w.w)*xr[4*c4+3];
        }
        ov[ro] = acc * scale;
    }

    // pack 24 bf16 -> 3 x uint4, store contiguous 48 B per thread (16-B aligned)
    unsigned int pk[12];
    #pragma unroll
    for (int d = 0; d < 12; d++)
        pk[d] = (unsigned)f2u(ov[2*d]) | ((unsigned)f2u(ov[2*d+1]) << 16);
    ushort_t* tp = (r6 >> 1) == 0 ? q : ((r6 >> 1) == 1 ? k : v);
    uint4* dst4 = (uint4*)(tp + (size_t)p*48 + (r6 & 1)*24);
    dst4[0] = make_uint4(pk[0], pk[1], pk[2],  pk[3]);
    dst4[1] = make_uint4(pk[4], pk[5], pk[6],  pk[7]);
    dst4[2] = make_uint4(pk[8], pk[9], pk[10], pk[11]);
}

// ------------- Kernel 2a: parallel partial reduction (48 blocks, 1 per channel) -
__global__ __launch_bounds__(256) void gatered_kernel(
    const float* __restrict__ chpart, float* __restrict__ msum)
{
    __shared__ float red[4];
    const int c = blockIdx.x;          // channel
    const int tid = threadIdx.x;
    float acc = 0.f;
    for (int b = tid; b < NBLK1; b += 256)
        acc += chpart[b*48 + c];
    acc += __shfl_xor(acc, 1);  acc += __shfl_xor(acc, 2);  acc += __shfl_xor(acc, 4);
    acc += __shfl_xor(acc, 8);  acc += __shfl_xor(acc, 16); acc += __shfl_xor(acc, 32);
    if ((tid & 63) == 0) red[tid >> 6] = acc;
    __syncthreads();
    if (tid == 0)
        msum[c] = (red[0] + red[1] + red[2] + red[3]) * (1.f / (float)HW_);
}

// ------------- Kernel 2b: ECA conv1d(k=7,pad=3) -> sigmoid ----------------------
__global__ void gate_kernel(const float* __restrict__ msum,
                            const float* __restrict__ wts,
                            float* __restrict__ gate)
{
    __shared__ float m[48];
    int t = threadIdx.x;
    if (t < 48) m[t] = msum[t];
    __syncthreads();
    if (t < 48){
        float a = 0.f;
        for (int kk = 0; kk < 7; kk++){
            int cc = t + kk - 3;
            if (cc >= 0 && cc < 48) a += wts[O_ECA + kk] * m[cc];
        }
        gate[t] = 1.f / (1.f + expf(-a));
    }
}

// ------------- Kernel 3: neighborhood attention (K=7, DIL=3), bf16 gathers ------
// grid (HW/128, 2 heads), block 256: 2 lanes per (px); each lane handles 12 ch.
__global__ __launch_bounds__(256) void attn_kernel(
    const ushort_t* __restrict__ q, const ushort_t* __restrict__ k,
    const ushort_t* __restrict__ v, const float* __restrict__ wts,
    float* __restrict__ aout)
{
    const int head = blockIdx.y;
    __shared__ float srpb[169];
    for (int i = threadIdx.x; i < 169; i += 256) srpb[i] = wts[O_RPB + head*169 + i];
    __syncthreads();

    const int tid  = threadIdx.x;
    const int px   = blockIdx.x * 128 + (tid >> 1);
    const int half = tid & 1;
    const int i = px / Wd, j = px % Wd;
    const int sti = wstart(i), stj = wstart(j);
    const int pbi = (sti - i) / 3 + 6;
    const int pbj = (stj - j) / 3 + 6;
    const int choff = head*24 + half*12;

    float qr[12];
    {
        const ushort4* qp = (const ushort4*)(q + px*48 + choff);
        #pragma unroll
        for (int b = 0; b < 3; b++){
            ushort4 uu = qp[b];
            qr[4*b]   = u2f(uu.x); qr[4*b+1] = u2f(uu.y);
            qr[4*b+2] = u2f(uu.z); qr[4*b+3] = u2f(uu.w);
        }
    }

    float l[49];
    float mx = -1e30f;
    #pragma unroll
    for (int xx = 0; xx < 7; xx++){
        int ii = sti + 3*xx;
        #pragma unroll
        for (int yy = 0; yy < 7; yy++){
            int jj = stj + 3*yy;
            const ushort4* kp = (const ushort4*)(k + (ii*Wd + jj)*48 + choff);
            float acc = 0.f;
            #pragma unroll
            for (int b = 0; b < 3; b++){
                ushort4 uu = kp[b];
                acc += qr[4*b]*u2f(uu.x) + qr[4*b+1]*u2f(uu.y)
                     + qr[4*b+2]*u2f(uu.z) + qr[4*b+3]*u2f(uu.w);
            }
            acc += __shfl_xor(acc, 1);               // combine channel halves
            acc += srpb[(pbi+xx)*13 + (pbj+yy)];
            l[xx*7+yy] = acc;
            mx = fmaxf(mx, acc);
        }
    }
    float s = 0.f;
    #pragma unroll
    for (int t = 0; t < 49; t++){ l[t] = __expf(l[t]-mx); s += l[t]; }
    float inv = 1.f / s;

    float acc[12];
    #pragma unroll
    for (int c = 0; c < 12; c++) acc[c] = 0.f;
    #pragma unroll
    for (int xx = 0; xx < 7; xx++){
        int ii = sti + 3*xx;
        #pragma unroll
        for (int yy = 0; yy < 7; yy++){
            const ushort4* vp = (const ushort4*)(v + (ii*Wd + stj + 3*yy)*48 + choff);
            float wgt = l[xx*7+yy] * inv;
            #pragma unroll
            for (int b = 0; b < 3; b++){
                ushort4 uu = vp[b];
                acc[4*b]   += wgt*u2f(uu.x); acc[4*b+1] += wgt*u2f(uu.y);
                acc[4*b+2] += wgt*u2f(uu.z); acc[4*b+3] += wgt*u2f(uu.w);
            }
        }
    }
    // planar fp32 out, coalesced (even lanes ch c, odd lanes ch 12+c)
    #pragma unroll
    for (int c = 0; c < 12; c++)
        aout[(choff + c)*HW_ + px] = acc[c];
}

// ------------- Kernel 4: proj + gate + residual (x2 = x + proj(aout)*gate) ------
// block 256 = 64 px * 4 wave-uniform o-groups (12 outputs each)
__global__ __launch_bounds__(256) void proj_kernel(
    const float* __restrict__ aout, const float* __restrict__ wts,
    const float* __restrict__ gate, const void* __restrict__ x,
    const int* __restrict__ mode, float* __restrict__ x2)
{
    __shared__ float sw[48*48];
    __shared__ float sbias[48];
    __shared__ float sg[48];
    const int tid = threadIdx.x;
    for (int i = tid; i < 2304; i += 256) sw[i] = wts[O_PROJW + i];
    if (tid < 48){
        sbias[tid] = wts[O_PROJB + tid];
        sg[tid]    = gate[tid];
    }
    __syncthreads();

    const int px = blockIdx.x * 64 + (tid & 63);
    const int og = tid >> 6;          // 0..3, wave-uniform
    const int ob = og * 12;

    float ar[48];
    #pragma unroll
    for (int c = 0; c < 48; c++) ar[c] = aout[c*HW_ + px];

    const float* xf = (const float*)x;
    const __hip_bfloat16* xb = (const __hip_bfloat16*)x;
    const int md = mode[0];
    #pragma unroll 2
    for (int oo = 0; oo < 12; oo++){
        int o = ob + oo;
        float acc = sbias[o];
        const float4* swr = (const float4*)&sw[o*48];
        #pragma unroll
        for (int c4 = 0; c4 < 12; c4++){
            float4 w = swr[c4];
            acc += w.x*ar[4*c4] + w.y*ar[4*c4+1] + w.z*ar[4*c4+2] + w.w*ar[4*c4+3];
        }
        float res = md ? xf[o*HW_ + px] : b2f(xb[o*HW_ + px]);
        x2[o*HW_ + px] = res + acc * sg[o];
    }
}

// ------------- Kernel 5: LN2 (inline) + pointwise1 (48 -> 254), bf16 out --------
__global__ __launch_bounds__(128) void pw1_kernel(
    const float* __restrict__ x2, const float* __restrict__ wts,
    ushort_t* __restrict__ t)
{
    int ob   = blockIdx.y * 64;
    int ocnt = min(64, 254 - ob);
    __shared__ float sw[64*48];
    __shared__ float sln[96];
    for (int i = threadIdx.x; i < ocnt*48; i += 128) sw[i] = wts[O_WIN + ob*48 + i];
    for (int i = threadIdx.x; i < 96;      i += 128) sln[i] = wts[O_LN2W + i];
    __syncthreads();

    int p = blockIdx.x * 128 + threadIdx.x;
    float xr[48];
    float mu = 0.f;
    #pragma unroll
    for (int c = 0; c < 48; c++){ xr[c] = x2[c*HW_ + p]; mu += xr[c]; }
    mu *= (1.f/48.f);
    float var = 0.f;
    #pragma unroll
    for (int c = 0; c < 48; c++){ float d = xr[c]-mu; var += d*d; }
    var *= (1.f/48.f);
    float rs = rsqrtf(var + 1e-5f);
    #pragma unroll
    for (int c = 0; c < 48; c++) xr[c] = (xr[c]-mu)*rs*sln[c] + sln[48+c];

    for (int o = 0; o < ocnt; o++){
        float acc = 0.f;
        const float4* swr = (const float4*)&sw[o*48];
        #pragma unroll
        for (int c4 = 0; c4 < 12; c4++){
            float4 w = swr[c4];
            acc += w.x*xr[4*c4] + w.y*xr[4*c4+1] + w.z*xr[4*c4+2] + w.w*xr[4*c4+3];
        }
        t[(ob+o)*HW_ + p] = f2u(acc);
    }
}

// ------------- Kernel 6: depthwise 3x3 + exact GeLU gating, bf16 in/out ---------
__global__ __launch_bounds__(256) void dw_kernel(
    const ushort_t* __restrict__ t, const float* __restrict__ wts,
    ushort_t* __restrict__ g)
{
    int ch = blockIdx.y;               // 0..126
    int p  = blockIdx.x * 256 + threadIdx.x;
    int i  = p / Wd, j = p % Wd;
    float w1[9], w2[9];
    #pragma unroll
    for (int s = 0; s < 9; s++){
        w1[s] = wts[O_WDW + ch*9 + s];
        w2[s] = wts[O_WDW + (ch+HIDc)*9 + s];
    }
    const ushort_t* t1 = t + (size_t)ch * HW_;
    const ushort_t* t2 = t + (size_t)(ch+HIDc) * HW_;
    float a1 = 0.f, a2 = 0.f;
    #pragma unroll
    for (int di = 0; di < 3; di++){
        int ii = i + di - 1;
        if (ii < 0 || ii >= 192) continue;
        #pragma unroll
        for (int dj = 0; dj < 3; dj++){
            int jj = j + dj - 1;
            if (jj < 0 || jj >= 192) continue;
            int off = ii*Wd + jj;
            a1 += w1[di*3+dj]*u2f(t1[off]);
            a2 += w2[di*3+dj]*u2f(t2[off]);
        }
    }
    float ge = a1 * 0.5f * (1.f + erff(a1 * 0.70710678118654752f)); // exact gelu
    g[(size_t)ch*HW_ + p] = f2u(ge * a2);
}

// ------------- Kernel 7: pointwise2 (127 -> 24x2) + final residual --------------
__global__ __launch_bounds__(128) void pw2_kernel(
    const ushort_t* __restrict__ g, const float* __restrict__ wts,
    const float* __restrict__ x2, void* __restrict__ outv,
    const int* __restrict__ mode)
{
    int ob = blockIdx.y * 24;          // 2 chunks of 24 output channels
    __shared__ float sw[24*127];
    for (int i = threadIdx.x; i < 24*127; i += 128) sw[i] = wts[O_WOUT + ob*127 + i];
    __syncthreads();

    int p = blockIdx.x * 128 + threadIdx.x;
    float acc[24];
    #pragma unroll
    for (int o = 0; o < 24; o++) acc[o] = 0.f;
    for (int c = 0; c < 127; c++){
        float gv = u2f(g[(size_t)c*HW_ + p]);
        #pragma unroll
        for (int o = 0; o < 24; o++) acc[o] += sw[o*127+c]*gv;
    }
    if (mode[0]){
        float* out = (float*)outv;
        #pragma unroll
        for (int o = 0; o < 24; o++){
            int oc = ob + o;
            out[(size_t)oc*HW_ + p] = x2[(size_t)oc*HW_ + p] + acc[o];
        }
    } else {
        __hip_bfloat16* out = (__hip_bfloat16*)outv;
        #pragma unroll
        for (int o = 0; o < 24; o++){
            int oc = ob + o;
            out[(size_t)oc*HW_ + p] =
                __float2bfloat16(x2[(size_t)oc*HW_ + p] + acc[o]);
        }
    }
}

extern "C" void kernel_launch(void* const* d_in, const int* in_sizes, int n_in,
                              void* d_out, int out_size, void* d_ws, size_t ws_size,
                              hipStream_t stream)
{
    (void)in_sizes; (void)n_in; (void)out_size;

    char* ws = (char*)d_ws;
    // region R (aliased): t bf16 [254][HW] = 18,726,912 B; inside it live
    //   q,k,v bf16 [HW][48] (3,538,944 B each) + aout fp32 [48][HW] (7,077,888 B)
    ushort_t* q    = (ushort_t*)(ws);
    ushort_t* k    = (ushort_t*)(ws + 3538944);
    ushort_t* v    = (ushort_t*)(ws + 7077888);
    float*    aout = (float*)   (ws + 10616832);
    ushort_t* t    = (ushort_t*)(ws);
    float*    x2   = (float*)   (ws + 18726912);
    ushort_t* g    = (ushort_t*)(ws + 25804800);
    float*    gate = (float*)   (ws + 35168448);
    int*      mode = (int*)     (ws + 35168640);
    float*    wts  = (float*)   (ws + 35168656);
    float*    chpart=(float*)   (ws + 35168656 + (size_t)WTS_LEN*4); // [NBLK1][48]
    float*    msum = chpart + (size_t)NBLK1*48;                      // [48]
    ushort_t* qkvbf= (ushort_t*)(msum + 48);                         // [6912] bf16

    size_t need = 35168656 + (size_t)WTS_LEN*4 + (size_t)NBLK1*48*4 + 48*4 + 6912*2;
    if (ws_size < need) return;

    detect_kernel<<<1, 256, 0, stream>>>((const ushort_t*)d_in[0], mode);
    convert_kernel<<<14, 256, 0, stream>>>(
        d_in[1], d_in[2], d_in[3], d_in[4], d_in[5], d_in[6], d_in[7],
        d_in[8], d_in[9], d_in[10], d_in[11], d_in[12], d_in[13], mode, wts, qkvbf);

    ln1qkv_kernel<<<dim3(NBLK1), 192, 0, stream>>>(d_in[0], mode, wts, qkvbf,
                                                   q, k, v, chpart);
    gatered_kernel<<<48, 256, 0, stream>>>(chpart, msum);
    gate_kernel<<<1, 64, 0, stream>>>(msum, wts, gate);
    attn_kernel<<<dim3(HW_/128, 2), 256, 0, stream>>>(q, k, v, wts, aout);
    proj_kernel<<<dim3(HW_/64), 256, 0, stream>>>(aout, wts, gate, d_in[0],
                                                  mode, x2);
    pw1_kernel<<<dim3(HW_/128, 4), 128, 0, stream>>>(x2, wts, t);
    dw_kernel<<<dim3(HW_/256, 127), 256, 0, stream>>>(t, wts, g);
    pw2_kernel<<<dim3(HW_/128, 2), 128, 0, stream>>>(g, wts, x2, d_out, mode);
}

// Round 7
// 289.489 us; speedup vs baseline: 2.4011x; 1.0301x over previous
//
#include <hip/hip_runtime.h>
#include <hip/hip_bf16.h>
#include <math.h>

#define HW_ (192*192)
#define Wd 192
#define HIDc 127
#define NBLK1 (HW_/32)   // 1152 ln1qkv blocks

// fp32 weight-copy offsets inside ws "wts" region
#define O_LN1W 0
#define O_QKVW 96
#define O_QKVB 7008
#define O_RPB  7152
#define O_PROJW 7490
#define O_PROJB 9794
#define O_ECA  9842
#define O_LN2W 9849
#define O_WIN  9945
#define O_WDW  22137
#define O_WOUT 24423
#define WTS_LEN 30519

typedef unsigned short ushort_t;

__device__ __forceinline__ float b2f(__hip_bfloat16 v){ return __bfloat162float(v); }
__device__ __forceinline__ float u2f(ushort_t h){ return __uint_as_float(((unsigned)h)<<16); }
__device__ __forceinline__ ushort_t f2u(float f){
    __hip_bfloat16 h = __float2bfloat16(f);
    union { __hip_bfloat16 b; ushort_t u; } c; c.b = h; return c.u;
}

__device__ __forceinline__ int wstart(int i){
    // L=192, K=7, DIL=3 closed form of _window_starts
    if (i < 9) return i % 3;
    if (i >= 183) return 171 + (i % 3);
    return i - 9;
}

// ------------- Kernel A: detect input dtype (bf16 vs fp32) ----------------------
__global__ void detect_kernel(const ushort_t* __restrict__ xu, int* __restrict__ mode)
{
    __shared__ int sbad;
    if (threadIdx.x == 0) sbad = 0;
    __syncthreads();
    int bad = 0;
    for (int t = threadIdx.x; t < 16384; t += 256){
        unsigned int u = xu[2*t];
        float f = __uint_as_float(u << 16);
        if (!(fabsf(f) < 100.f)) bad++;
    }
    atomicAdd(&sbad, bad);
    __syncthreads();
    if (threadIdx.x == 0) mode[0] = (sbad > 1000) ? 1 : 0;
}

// ------------- Kernel B: convert weights to fp32 (+ qkv bf16 copy + woutT) ------
__global__ void convert_kernel(
    const void* p0, const void* p1, const void* p2, const void* p3,
    const void* p4, const void* p5, const void* p6, const void* p7,
    const void* p8, const void* p9, const void* p10, const void* p11,
    const void* p12, const int* __restrict__ mode, float* __restrict__ wts,
    ushort_t* __restrict__ qkvbf, float* __restrict__ woutT)
{
    const void* ps[13] = {p0,p1,p2,p3,p4,p5,p6,p7,p8,p9,p10,p11,p12};
    const int sz[13]  = {48,48,6912,144,338,2304,48,7,48,48,12192,2286,6096};
    const int off[13] = {O_LN1W,48,O_QKVW,O_QKVB,O_RPB,O_PROJW,O_PROJB,O_ECA,
                         O_LN2W,9897,O_WIN,O_WDW,O_WOUT};
    int b = blockIdx.x;
    if (b == 13){   // packed bf16 copy of qkv_w for ln1qkv LDS staging
        if (mode[0]){
            const float* s = (const float*)p2;
            for (int i = threadIdx.x; i < 6912; i += 256) qkvbf[i] = f2u(s[i]);
        } else {
            const ushort_t* s = (const ushort_t*)p2;
            for (int i = threadIdx.x; i < 6912; i += 256) qkvbf[i] = s[i];
        }
        return;
    }
    if (b == 14){   // transposed w_out: woutT[c*48+o] = w_out[o*127+c]
        if (mode[0]){
            const float* s = (const float*)p12;
            for (int i = threadIdx.x; i < 6096; i += 256){
                int c = i / 48, o = i - c*48;
                woutT[i] = s[o*127 + c];
            }
        } else {
            const __hip_bfloat16* s = (const __hip_bfloat16*)p12;
            for (int i = threadIdx.x; i < 6096; i += 256){
                int c = i / 48, o = i - c*48;
                woutT[i] = b2f(s[o*127 + c]);
            }
        }
        return;
    }
    int n = sz[b];
    float* dst = wts + off[b];
    if (mode[0]){
        const float* s = (const float*)ps[b];
        for (int i = threadIdx.x; i < n; i += 256) dst[i] = s[i];
    } else {
        const __hip_bfloat16* s = (const __hip_bfloat16*)ps[b];
        for (int i = threadIdx.x; i < n; i += 256) dst[i] = b2f(s[i]);
    }
}

// ------------- Kernel 1: LN1 + QKV proj (6 thr/px) + ECA partial sums -----------
__global__ __launch_bounds__(192) void ln1qkv_kernel(
    const void* __restrict__ x, const int* __restrict__ mode,
    const float* __restrict__ wts, const ushort_t* __restrict__ qkvbf,
    ushort_t* __restrict__ q, ushort_t* __restrict__ k, ushort_t* __restrict__ v,
    float* __restrict__ chpart)
{
    __shared__ ushort_t ssw[144*48];      // 13824 B, bf16 weights
    __shared__ float sx[32*49];           // 6272 B (pad 49)
    __shared__ float sb[144];
    __shared__ float sln[96];

    const int tid = threadIdx.x;
    const int px_l = tid & 31;
    const int r6   = tid >> 5;            // 0..5, wave-uniform
    const int p0   = blockIdx.x * 32;
    const int p    = p0 + px_l;

    {   // weight stage: coalesced dword copy of 3456 dwords
        const unsigned int* srcw = (const unsigned int*)qkvbf;
        unsigned int* dstw = (unsigned int*)ssw;
        for (int i = tid; i < 3456; i += 192) dstw[i] = srcw[i];
    }
    for (int i = tid; i < 144; i += 192) sb[i] = wts[O_QKVB + i];
    for (int i = tid; i < 96;  i += 192) sln[i] = wts[O_LN1W + i];

    // x tile load, planar-coalesced
    if (mode[0]){
        const float* xf = (const float*)x;
        for (int idx = tid; idx < 32*48; idx += 192){
            int c = idx >> 5, pl = idx & 31;
            sx[pl*49 + c] = xf[c*HW_ + p0 + pl];
        }
    } else {
        const __hip_bfloat16* xb = (const __hip_bfloat16*)x;
        for (int idx = tid; idx < 32*48; idx += 192){
            int c = idx >> 5, pl = idx & 31;
            sx[pl*49 + c] = b2f(xb[c*HW_ + p0 + pl]);
        }
    }
    __syncthreads();

    float xr[48];
    float mu = 0.f;
    #pragma unroll
    for (int c = 0; c < 48; c++){ xr[c] = sx[px_l*49 + c]; mu += xr[c]; }
    mu *= (1.f/48.f);
    float var = 0.f;
    #pragma unroll
    for (int c = 0; c < 48; c++){ float d = xr[c]-mu; var += d*d; }
    var *= (1.f/48.f);
    float rs = rsqrtf(var + 1e-5f);
    #pragma unroll
    for (int c = 0; c < 48; c++) xr[c] = (xr[c]-mu)*rs*sln[c] + sln[48+c];

    // ECA per-block partials: wave 0 (lanes 0..31 = px r6=0, 32..63 same px r6=1)
    if (tid < 64){
        #pragma unroll
        for (int c = 0; c < 48; c++){
            float s = xr[c];
            s += __shfl_xor(s, 1);  s += __shfl_xor(s, 2);  s += __shfl_xor(s, 4);
            s += __shfl_xor(s, 8);  s += __shfl_xor(s, 16); s += __shfl_xor(s, 32);
            if (tid == 0) chpart[blockIdx.x*48 + c] = s * 0.5f;  // halves double-count
        }
    }

    const int rbase = r6 * 24;
    const float scale = (r6 < 2) ? 0.20412414523193154f : 1.0f;
    float ov[24];
    #pragma unroll 4
    for (int ro = 0; ro < 24; ro++){
        int r = rbase + ro;
        float acc = sb[r];
        const ushort4* wr = (const ushort4*)&ssw[r*48];
        #pragma unroll
        for (int c4 = 0; c4 < 12; c4++){
            ushort4 w = wr[c4];
            acc += u2f(w.x)*xr[4*c4]   + u2f(w.y)*xr[4*c4+1]
                 + u2f(w.z)*xr[4*c4+2] + u2f(w.w)*xr[4*c4+3];
        }
        ov[ro] = acc * scale;
    }

    // pack 24 bf16 -> 3 x uint4, store contiguous 48 B per thread (16-B aligned)
    unsigned int pk[12];
    #pragma unroll
    for (int d = 0; d < 12; d++)
        pk[d] = (unsigned)f2u(ov[2*d]) | ((unsigned)f2u(ov[2*d+1]) << 16);
    ushort_t* tp = (r6 >> 1) == 0 ? q : ((r6 >> 1) == 1 ? k : v);
    uint4* dst4 = (uint4*)(tp + (size_t)p*48 + (r6 & 1)*24);
    dst4[0] = make_uint4(pk[0], pk[1], pk[2],  pk[3]);
    dst4[1] = make_uint4(pk[4], pk[5], pk[6],  pk[7]);
    dst4[2] = make_uint4(pk[8], pk[9], pk[10], pk[11]);
}

// ------------- Kernel 2a: parallel partial reduction (48 blocks, 1 per channel) -
__global__ __launch_bounds__(256) void gatered_kernel(
    const float* __restrict__ chpart, float* __restrict__ msum)
{
    __shared__ float red[4];
    const int c = blockIdx.x;          // channel
    const int tid = threadIdx.x;
    float acc = 0.f;
    for (int b = tid; b < NBLK1; b += 256)
        acc += chpart[b*48 + c];
    acc += __shfl_xor(acc, 1);  acc += __shfl_xor(acc, 2);  acc += __shfl_xor(acc, 4);
    acc += __shfl_xor(acc, 8);  acc += __shfl_xor(acc, 16); acc += __shfl_xor(acc, 32);
    if ((tid & 63) == 0) red[tid >> 6] = acc;
    __syncthreads();
    if (tid == 0)
        msum[c] = (red[0] + red[1] + red[2] + red[3]) * (1.f / (float)HW_);
}

// ------------- Kernel 2b: ECA conv1d(k=7,pad=3) -> sigmoid ----------------------
__global__ void gate_kernel(const float* __restrict__ msum,
                            const float* __restrict__ wts,
                            float* __restrict__ gate)
{
    __shared__ float m[48];
    int t = threadIdx.x;
    if (t < 48) m[t] = msum[t];
    __syncthreads();
    if (t < 48){
        float a = 0.f;
        for (int kk = 0; kk < 7; kk++){
            int cc = t + kk - 3;
            if (cc >= 0 && cc < 48) a += wts[O_ECA + kk] * m[cc];
        }
        gate[t] = 1.f / (1.f + expf(-a));
    }
}

// ------------- Kernel 3: neighborhood attention (K=7, DIL=3), bf16 gathers ------
__global__ __launch_bounds__(256) void attn_kernel(
    const ushort_t* __restrict__ q, const ushort_t* __restrict__ k,
    const ushort_t* __restrict__ v, const float* __restrict__ wts,
    float* __restrict__ aout)
{
    const int head = blockIdx.y;
    __shared__ float srpb[169];
    for (int i = threadIdx.x; i < 169; i += 256) srpb[i] = wts[O_RPB + head*169 + i];
    __syncthreads();

    const int tid  = threadIdx.x;
    const int px   = blockIdx.x * 128 + (tid >> 1);
    const int half = tid & 1;
    const int i = px / Wd, j = px % Wd;
    const int sti = wstart(i), stj = wstart(j);
    const int pbi = (sti - i) / 3 + 6;
    const int pbj = (stj - j) / 3 + 6;
    const int choff = head*24 + half*12;

    float qr[12];
    {
        const ushort4* qp = (const ushort4*)(q + px*48 + choff);
        #pragma unroll
        for (int b = 0; b < 3; b++){
            ushort4 uu = qp[b];
            qr[4*b]   = u2f(uu.x); qr[4*b+1] = u2f(uu.y);
            qr[4*b+2] = u2f(uu.z); qr[4*b+3] = u2f(uu.w);
        }
    }

    float l[49];
    float mx = -1e30f;
    #pragma unroll
    for (int xx = 0; xx < 7; xx++){
        int ii = sti + 3*xx;
        #pragma unroll
        for (int yy = 0; yy < 7; yy++){
            int jj = stj + 3*yy;
            const ushort4* kp = (const ushort4*)(k + (ii*Wd + jj)*48 + choff);
            float acc = 0.f;
            #pragma unroll
            for (int b = 0; b < 3; b++){
                ushort4 uu = kp[b];
                acc += qr[4*b]*u2f(uu.x) + qr[4*b+1]*u2f(uu.y)
                     + qr[4*b+2]*u2f(uu.z) + qr[4*b+3]*u2f(uu.w);
            }
            acc += __shfl_xor(acc, 1);               // combine channel halves
            acc += srpb[(pbi+xx)*13 + (pbj+yy)];
            l[xx*7+yy] = acc;
            mx = fmaxf(mx, acc);
        }
    }
    float s = 0.f;
    #pragma unroll
    for (int t = 0; t < 49; t++){ l[t] = __expf(l[t]-mx); s += l[t]; }
    float inv = 1.f / s;

    float acc[12];
    #pragma unroll
    for (int c = 0; c < 12; c++) acc[c] = 0.f;
    #pragma unroll
    for (int xx = 0; xx < 7; xx++){
        int ii = sti + 3*xx;
        #pragma unroll
        for (int yy = 0; yy < 7; yy++){
            const ushort4* vp = (const ushort4*)(v + (ii*Wd + stj + 3*yy)*48 + choff);
            float wgt = l[xx*7+yy] * inv;
            #pragma unroll
            for (int b = 0; b < 3; b++){
                ushort4 uu = vp[b];
                acc[4*b]   += wgt*u2f(uu.x); acc[4*b+1] += wgt*u2f(uu.y);
                acc[4*b+2] += wgt*u2f(uu.z); acc[4*b+3] += wgt*u2f(uu.w);
            }
        }
    }
    // planar fp32 out, coalesced (even lanes ch c, odd lanes ch 12+c)
    #pragma unroll
    for (int c = 0; c < 12; c++)
        aout[(choff + c)*HW_ + px] = acc[c];
}

// ------------- Kernel 4: proj + gate + residual -- weights via scalar K$ --------
// block 256 = 64 px * 4 wave-uniform o-groups (12 outputs each); no LDS.
__global__ __launch_bounds__(256) void proj_kernel(
    const float* __restrict__ aout, const float* __restrict__ wts,
    const float* __restrict__ gate, const void* __restrict__ x,
    const int* __restrict__ mode, float* __restrict__ x2)
{
    const int tid = threadIdx.x;
    const int px = blockIdx.x * 64 + (tid & 63);
    const int og = tid >> 6;          // 0..3, wave-uniform
    const int ob = og * 12;

    float ar[48];
    #pragma unroll
    for (int c = 0; c < 48; c++) ar[c] = aout[c*HW_ + px];

    const float* xf = (const float*)x;
    const __hip_bfloat16* xb = (const __hip_bfloat16*)x;
    const int md = mode[0];
    #pragma unroll 2
    for (int oo = 0; oo < 12; oo++){
        int o = ob + oo;
        float acc = wts[O_PROJB + o];                 // uniform -> s_load
        const float4* swr = (const float4*)&wts[O_PROJW + o*48];  // uniform
        #pragma unroll
        for (int c4 = 0; c4 < 12; c4++){
            float4 w = swr[c4];
            acc += w.x*ar[4*c4] + w.y*ar[4*c4+1] + w.z*ar[4*c4+2] + w.w*ar[4*c4+3];
        }
        float res = md ? xf[o*HW_ + px] : b2f(xb[o*HW_ + px]);
        x2[o*HW_ + px] = res + acc * gate[o];
    }
}

// ------------- Kernel 5: LN2 + pointwise1 (48 -> 254) -- weights via scalar K$ --
__global__ __launch_bounds__(128) void pw1_kernel(
    const float* __restrict__ x2, const float* __restrict__ wts,
    ushort_t* __restrict__ t)
{
    int ob   = blockIdx.y * 64;
    int ocnt = min(64, 254 - ob);

    int p = blockIdx.x * 128 + threadIdx.x;
    float xr[48];
    float mu = 0.f;
    #pragma unroll
    for (int c = 0; c < 48; c++){ xr[c] = x2[c*HW_ + p]; mu += xr[c]; }
    mu *= (1.f/48.f);
    float var = 0.f;
    #pragma unroll
    for (int c = 0; c < 48; c++){ float d = xr[c]-mu; var += d*d; }
    var *= (1.f/48.f);
    float rs = rsqrtf(var + 1e-5f);
    #pragma unroll
    for (int c = 0; c < 48; c++)
        xr[c] = (xr[c]-mu)*rs*wts[O_LN2W + c] + wts[O_LN2W + 48 + c]; // uniform

    for (int o = 0; o < ocnt; o++){
        float acc = 0.f;
        const float4* swr = (const float4*)&wts[O_WIN + (ob+o)*48];  // uniform
        #pragma unroll
        for (int c4 = 0; c4 < 12; c4++){
            float4 w = swr[c4];
            acc += w.x*xr[4*c4] + w.y*xr[4*c4+1] + w.z*xr[4*c4+2] + w.w*xr[4*c4+3];
        }
        t[(ob+o)*HW_ + p] = f2u(acc);
    }
}

// ------------- Kernel 6: depthwise 3x3 + exact GeLU gating, bf16 in/out ---------
__global__ __launch_bounds__(256) void dw_kernel(
    const ushort_t* __restrict__ t, const float* __restrict__ wts,
    ushort_t* __restrict__ g)
{
    int ch = blockIdx.y;               // 0..126
    int p  = blockIdx.x * 256 + threadIdx.x;
    int i  = p / Wd, j = p % Wd;
    float w1[9], w2[9];
    #pragma unroll
    for (int s = 0; s < 9; s++){
        w1[s] = wts[O_WDW + ch*9 + s];
        w2[s] = wts[O_WDW + (ch+HIDc)*9 + s];
    }
    const ushort_t* t1 = t + (size_t)ch * HW_;
    const ushort_t* t2 = t + (size_t)(ch+HIDc) * HW_;
    float a1 = 0.f, a2 = 0.f;
    #pragma unroll
    for (int di = 0; di < 3; di++){
        int ii = i + di - 1;
        if (ii < 0 || ii >= 192) continue;
        #pragma unroll
        for (int dj = 0; dj < 3; dj++){
            int jj = j + dj - 1;
            if (jj < 0 || jj >= 192) continue;
            int off = ii*Wd + jj;
            a1 += w1[di*3+dj]*u2f(t1[off]);
            a2 += w2[di*3+dj]*u2f(t2[off]);
        }
    }
    float ge = a1 * 0.5f * (1.f + erff(a1 * 0.70710678118654752f)); // exact gelu
    g[(size_t)ch*HW_ + p] = f2u(ge * a2);
}

// ------------- Kernel 7: pointwise2 (woutT scalar-K$) + final residual ----------
// grid (HW/128, 2): 24 outputs per y-chunk; weights transposed [c][48] -> per-c
// contiguous 24 floats load as s_load_dwordx4 x6, shared by all lanes.
__global__ __launch_bounds__(128) void pw2_kernel(
    const ushort_t* __restrict__ g, const float* __restrict__ woutT,
    const float* __restrict__ x2, void* __restrict__ outv,
    const int* __restrict__ mode)
{
    const int ob = blockIdx.y * 24;
    const int p  = blockIdx.x * 128 + threadIdx.x;
    float acc[24];
    #pragma unroll
    for (int o = 0; o < 24; o++) acc[o] = 0.f;
    #pragma unroll 4
    for (int c = 0; c < 127; c++){
        float gv = u2f(g[(size_t)c*HW_ + p]);
        const float* wr = woutT + c*48 + ob;          // uniform -> s_load
        #pragma unroll
        for (int o = 0; o < 24; o++) acc[o] += wr[o]*gv;
    }
    if (mode[0]){
        float* out = (float*)outv;
        #pragma unroll
        for (int o = 0; o < 24; o++){
            int oc = ob + o;
            out[(size_t)oc*HW_ + p] = x2[(size_t)oc*HW_ + p] + acc[o];
        }
    } else {
        __hip_bfloat16* out = (__hip_bfloat16*)outv;
        #pragma unroll
        for (int o = 0; o < 24; o++){
            int oc = ob + o;
            out[(size_t)oc*HW_ + p] =
                __float2bfloat16(x2[(size_t)oc*HW_ + p] + acc[o]);
        }
    }
}

extern "C" void kernel_launch(void* const* d_in, const int* in_sizes, int n_in,
                              void* d_out, int out_size, void* d_ws, size_t ws_size,
                              hipStream_t stream)
{
    (void)in_sizes; (void)n_in; (void)out_size;

    char* ws = (char*)d_ws;
    // region R (aliased): t bf16 [254][HW] = 18,726,912 B; inside it live
    //   q,k,v bf16 [HW][48] (3,538,944 B each) + aout fp32 [48][HW] (7,077,888 B)
    ushort_t* q    = (ushort_t*)(ws);
    ushort_t* k    = (ushort_t*)(ws + 3538944);
    ushort_t* v    = (ushort_t*)(ws + 7077888);
    float*    aout = (float*)   (ws + 10616832);
    ushort_t* t    = (ushort_t*)(ws);
    float*    x2   = (float*)   (ws + 18726912);
    ushort_t* g    = (ushort_t*)(ws + 25804800);
    float*    gate = (float*)   (ws + 35168448);
    int*      mode = (int*)     (ws + 35168640);
    float*    wts  = (float*)   (ws + 35168656);
    float*    chpart=(float*)   (ws + 35168656 + (size_t)WTS_LEN*4); // [NBLK1][48]
    float*    msum = chpart + (size_t)NBLK1*48;                      // [48]
    ushort_t* qkvbf= (ushort_t*)(msum + 48);                         // [6912] bf16
    float*    woutT= (float*)(qkvbf + 6912);                         // [127*48]

    size_t need = 35168656 + (size_t)WTS_LEN*4 + (size_t)NBLK1*48*4 + 48*4
                + 6912*2 + 6096*4;
    if (ws_size < need) return;

    detect_kernel<<<1, 256, 0, stream>>>((const ushort_t*)d_in[0], mode);
    convert_kernel<<<15, 256, 0, stream>>>(
        d_in[1], d_in[2], d_in[3], d_in[4], d_in[5], d_in[6], d_in[7],
        d_in[8], d_in[9], d_in[10], d_in[11], d_in[12], d_in[13], mode, wts,
        qkvbf, woutT);

    ln1qkv_kernel<<<dim3(NBLK1), 192, 0, stream>>>(d_in[0], mode, wts, qkvbf,
                                                   q, k, v, chpart);
    gatered_kernel<<<48, 256, 0, stream>>>(chpart, msum);
    gate_kernel<<<1, 64, 0, stream>>>(msum, wts, gate);
    attn_kernel<<<dim3(HW_/128, 2), 256, 0, stream>>>(q, k, v, wts, aout);
    proj_kernel<<<dim3(HW_/64), 256, 0, stream>>>(aout, wts, gate, d_in[0],
                                                  mode, x2);
    pw1_kernel<<<dim3(HW_/128, 4), 128, 0, stream>>>(x2, wts, t);
    dw_kernel<<<dim3(HW_/256, 127), 256, 0, stream>>>(t, wts, g);
    pw2_kernel<<<dim3(HW_/128, 2), 128, 0, stream>>>(g, woutT, x2, d_out, mode);
}